// Round 1
// baseline (1485.518 us; speedup 1.0000x reference)
//
#include <hip/hip_runtime.h>

#define N_NODES 50000
#define D 128

// ---------------------------------------------------------------------------
// deg[dst] += 1 per edge (fp32 HW atomic; deg is identical for both layers)
// ---------------------------------------------------------------------------
__global__ void deg_kernel(const int* __restrict__ dst,
                           float* __restrict__ deg, int n_edges) {
    int e = blockIdx.x * blockDim.x + threadIdx.x;
    if (e < n_edges) unsafeAtomicAdd(&deg[dst[e]], 1.0f);
}

// ---------------------------------------------------------------------------
// One wave (64 lanes) per edge: gather feat[src] row (float2/lane = 512B),
// scatter-add into agg[dst] row with HW fp32 atomics.
// ---------------------------------------------------------------------------
__global__ void agg_kernel(const float* __restrict__ feat,
                           const int* __restrict__ src,
                           const int* __restrict__ dst,
                           float* __restrict__ agg, int n_edges) {
    int gid  = blockIdx.x * blockDim.x + threadIdx.x;
    int edge = gid >> 6;
    int lane = threadIdx.x & 63;
    if (edge >= n_edges) return;
    int s = src[edge];
    int d = dst[edge];
    const float2 v =
        *reinterpret_cast<const float2*>(&feat[(size_t)s * D + lane * 2]);
    float* ap = &agg[(size_t)d * D + lane * 2];
    unsafeAtomicAdd(ap,     v.x);
    unsafeAtomicAdd(ap + 1, v.y);
}

// ---------------------------------------------------------------------------
// Per-node: mean = agg/max(deg,1); out = relu(mean@Wl + b + x@Wr)
// block = 128 threads = one node; thread j computes out[n][j].
// x row and mean row staged in LDS; W reads coalesced across j (L2-hot).
// ---------------------------------------------------------------------------
__global__ void sage_layer(const float* __restrict__ x,
                           const float* __restrict__ agg,
                           const float* __restrict__ deg,
                           const float* __restrict__ Wl,
                           const float* __restrict__ b,
                           const float* __restrict__ Wr,
                           float* __restrict__ out) {
    int n = blockIdx.x;
    int j = threadIdx.x;  // 0..127

    __shared__ float xs[D];
    __shared__ float ms[D];

    float dg  = deg[n];
    float inv = 1.0f / (dg > 1.0f ? dg : 1.0f);

    xs[j] = x[(size_t)n * D + j];
    ms[j] = agg[(size_t)n * D + j] * inv;
    __syncthreads();

    float acc = b[j];
#pragma unroll
    for (int k = 0; k < D; ++k) {
        acc += ms[k] * Wl[k * D + j] + xs[k] * Wr[k * D + j];
    }
    out[(size_t)n * D + j] = acc > 0.0f ? acc : 0.0f;
}

extern "C" void kernel_launch(void* const* d_in, const int* in_sizes, int n_in,
                              void* d_out, int out_size, void* d_ws, size_t ws_size,
                              hipStream_t stream) {
    const float* x   = (const float*)d_in[0];
    const int*   ei  = (const int*)  d_in[1];
    const float* W1l = (const float*)d_in[2];
    const float* b1  = (const float*)d_in[3];
    const float* W1r = (const float*)d_in[4];
    const float* W2l = (const float*)d_in[5];
    const float* b2  = (const float*)d_in[6];
    const float* W2r = (const float*)d_in[7];
    float*       out = (float*)d_out;

    const int n_edges = in_sizes[1] / 2;
    const int* src = ei;
    const int* dst = ei + n_edges;

    char* ws = (char*)d_ws;
    float* deg = (float*)ws;
    float* agg = (float*)(ws + ((N_NODES * sizeof(float) + 255) / 256 * 256));
    float* h   = agg + (size_t)N_NODES * D;

    const size_t agg_bytes = (size_t)N_NODES * D * sizeof(float);

    hipMemsetAsync(deg, 0, N_NODES * sizeof(float), stream);
    hipMemsetAsync(agg, 0, agg_bytes, stream);

    deg_kernel<<<(n_edges + 255) / 256, 256, 0, stream>>>(dst, deg, n_edges);

    // ---- layer 1 ----
    {
        int waves_threads = n_edges * 64;
        agg_kernel<<<(waves_threads + 255) / 256, 256, 0, stream>>>(
            x, src, dst, agg, n_edges);
        sage_layer<<<N_NODES, D, 0, stream>>>(x, agg, deg, W1l, b1, W1r, h);
    }

    // ---- layer 2 ----
    {
        hipMemsetAsync(agg, 0, agg_bytes, stream);
        int waves_threads = n_edges * 64;
        agg_kernel<<<(waves_threads + 255) / 256, 256, 0, stream>>>(
            h, src, dst, agg, n_edges);
        sage_layer<<<N_NODES, D, 0, stream>>>(h, agg, deg, W2l, b2, W2r, out);
    }
}

// Round 2
// 648.765 us; speedup vs baseline: 2.2898x; 2.2898x over previous
//
#include <hip/hip_runtime.h>

#define N_NODES 50000
#define D 128
#define SCAN_T 1024

// ---------------------------------------------------------------------------
// CSR build step 1: histogram of dst
// ---------------------------------------------------------------------------
__global__ void hist_kernel(const int* __restrict__ dst,
                            int* __restrict__ cnt, int n_edges) {
    int e = blockIdx.x * blockDim.x + threadIdx.x;
    if (e < n_edges) atomicAdd(&cnt[dst[e]], 1);
}

// ---------------------------------------------------------------------------
// CSR build step 2: exclusive scan of cnt -> rowptr (and cursor copy).
// Single block, 1024 threads, chunked Hillis-Steele.
// ---------------------------------------------------------------------------
__global__ void scan_kernel(const int* __restrict__ cnt,
                            int* __restrict__ rowptr,
                            int* __restrict__ cursor) {
    __shared__ int sums[SCAN_T];
    const int t = threadIdx.x;
    const int C = (N_NODES + SCAN_T - 1) / SCAN_T;  // 49
    const int base = t * C;

    int s = 0;
    for (int i = 0; i < C; ++i) {
        int idx = base + i;
        if (idx < N_NODES) s += cnt[idx];
    }
    sums[t] = s;
    __syncthreads();

    for (int off = 1; off < SCAN_T; off <<= 1) {
        int tmp = (t >= off) ? sums[t - off] : 0;
        __syncthreads();
        sums[t] += tmp;
        __syncthreads();
    }

    int run = sums[t] - s;  // exclusive prefix of this thread's chunk
    for (int i = 0; i < C; ++i) {
        int idx = base + i;
        if (idx < N_NODES) {
            rowptr[idx] = run;
            cursor[idx] = run;
            run += cnt[idx];
        }
    }
    if (t == SCAN_T - 1) rowptr[N_NODES] = run;
}

// ---------------------------------------------------------------------------
// CSR build step 3: scatter src ids into dst-sorted order
// ---------------------------------------------------------------------------
__global__ void scatter_kernel(const int* __restrict__ src,
                               const int* __restrict__ dst,
                               int* __restrict__ cursor,
                               int* __restrict__ col, int n_edges) {
    int e = blockIdx.x * blockDim.x + threadIdx.x;
    if (e < n_edges) {
        int p = atomicAdd(&cursor[dst[e]], 1);
        col[p] = src[e];
    }
}

// ---------------------------------------------------------------------------
// Fused layer: per-node gather-sum over CSR (no atomics) + mean + GEMM + ReLU.
// block = 128 threads = one node; thread j owns output column j.
// ---------------------------------------------------------------------------
__global__ void sage_fused(const float* __restrict__ feat,
                           const int* __restrict__ rowptr,
                           const int* __restrict__ col,
                           const float* __restrict__ Wl,
                           const float* __restrict__ b,
                           const float* __restrict__ Wr,
                           float* __restrict__ out) {
    const int n = blockIdx.x;
    const int j = threadIdx.x;  // 0..127

    __shared__ float xs[D];
    __shared__ float ms[D];

    const int e0 = rowptr[n];
    const int e1 = rowptr[n + 1];

    float acc = 0.0f;
    for (int e = e0; e < e1; ++e) {
        int s = col[e];  // same for all lanes (broadcast, L1-hot)
        acc += feat[(size_t)s * D + j];
    }
    const int deg = e1 - e0;
    const float inv = deg > 0 ? 1.0f / (float)deg : 0.0f;

    ms[j] = acc * inv;
    xs[j] = feat[(size_t)n * D + j];
    __syncthreads();

    float r = b[j];
#pragma unroll
    for (int k = 0; k < D; ++k) {
        r += ms[k] * Wl[k * D + j] + xs[k] * Wr[k * D + j];
    }
    out[(size_t)n * D + j] = r > 0.0f ? r : 0.0f;
}

extern "C" void kernel_launch(void* const* d_in, const int* in_sizes, int n_in,
                              void* d_out, int out_size, void* d_ws, size_t ws_size,
                              hipStream_t stream) {
    const float* x   = (const float*)d_in[0];
    const int*   ei  = (const int*)  d_in[1];
    const float* W1l = (const float*)d_in[2];
    const float* b1  = (const float*)d_in[3];
    const float* W1r = (const float*)d_in[4];
    const float* W2l = (const float*)d_in[5];
    const float* b2  = (const float*)d_in[6];
    const float* W2r = (const float*)d_in[7];
    float*       out = (float*)d_out;

    const int n_edges = in_sizes[1] / 2;
    const int* src = ei;
    const int* dst = ei + n_edges;

    // workspace layout
    char* ws = (char*)d_ws;
    int* cnt    = (int*)ws;                      // N
    int* rowptr = cnt + N_NODES;                 // N+1
    int* cursor = rowptr + (N_NODES + 1);        // N
    int* col    = cursor + N_NODES;              // E
    float* h    = (float*)(col + n_edges);       // N*D
    // total: ~0.6 MB + 2.56 MB + 25.6 MB

    // ---- CSR build (once; shared by both layers) ----
    hipMemsetAsync(cnt, 0, N_NODES * sizeof(int), stream);
    hist_kernel<<<(n_edges + 255) / 256, 256, 0, stream>>>(dst, cnt, n_edges);
    scan_kernel<<<1, SCAN_T, 0, stream>>>(cnt, rowptr, cursor);
    scatter_kernel<<<(n_edges + 255) / 256, 256, 0, stream>>>(src, dst, cursor,
                                                              col, n_edges);

    // ---- layer 1: x -> h ----
    sage_fused<<<N_NODES, D, 0, stream>>>(x, rowptr, col, W1l, b1, W1r, h);
    // ---- layer 2: h -> out ----
    sage_fused<<<N_NODES, D, 0, stream>>>(h, rowptr, col, W2l, b2, W2r, out);
}

// Round 3
// 351.329 us; speedup vs baseline: 4.2283x; 1.8466x over previous
//
#include <hip/hip_runtime.h>

#define N_NODES 50000
#define D 128
#define KDIM 256
#define SCAN_T 1024

typedef __attribute__((ext_vector_type(8))) short short8;
typedef __attribute__((ext_vector_type(4))) float f32x4;

__device__ __forceinline__ unsigned short f2bf(float f) {
    unsigned int u = __builtin_bit_cast(unsigned int, f);
    u += 0x7FFFu + ((u >> 16) & 1u);
    return (unsigned short)(u >> 16);
}
__device__ __forceinline__ float bflo(unsigned int u) {
    return __builtin_bit_cast(float, u << 16);
}
__device__ __forceinline__ float bfhi(unsigned int u) {
    return __builtin_bit_cast(float, u & 0xFFFF0000u);
}

// ---------------------------------------------------------------------------
// CSR build
// ---------------------------------------------------------------------------
__global__ void hist_kernel(const int* __restrict__ dst,
                            int* __restrict__ cnt, int n_edges) {
    int e = blockIdx.x * blockDim.x + threadIdx.x;
    if (e < n_edges) atomicAdd(&cnt[dst[e]], 1);
}

__global__ void scan_kernel(const int* __restrict__ cnt,
                            int* __restrict__ rowptr,
                            int* __restrict__ cursor) {
    __shared__ int sums[SCAN_T];
    const int t = threadIdx.x;
    const int C = (N_NODES + SCAN_T - 1) / SCAN_T;  // 49
    const int base = t * C;

    int s = 0;
    for (int i = 0; i < C; ++i) {
        int idx = base + i;
        if (idx < N_NODES) s += cnt[idx];
    }
    sums[t] = s;
    __syncthreads();

    for (int off = 1; off < SCAN_T; off <<= 1) {
        int tmp = (t >= off) ? sums[t - off] : 0;
        __syncthreads();
        sums[t] += tmp;
        __syncthreads();
    }

    int run = sums[t] - s;
    for (int i = 0; i < C; ++i) {
        int idx = base + i;
        if (idx < N_NODES) {
            rowptr[idx] = run;
            cursor[idx] = run;
            run += cnt[idx];
        }
    }
    if (t == SCAN_T - 1) rowptr[N_NODES] = run;
}

__global__ void scatter_kernel(const int* __restrict__ src,
                               const int* __restrict__ dst,
                               int* __restrict__ cursor,
                               int* __restrict__ col, int n_edges) {
    int e = blockIdx.x * blockDim.x + threadIdx.x;
    if (e < n_edges) {
        int p = atomicAdd(&cursor[dst[e]], 1);
        col[p] = src[e];
    }
}

// ---------------------------------------------------------------------------
// x (fp32) -> A[n][128..255] (bf16)
// ---------------------------------------------------------------------------
__global__ void convert_x(const float* __restrict__ x,
                          unsigned short* __restrict__ A) {
    int t = blockIdx.x * blockDim.x + threadIdx.x;
    int n = t >> 5;             // 32 threads per node row
    int c4 = (t & 31) * 4;
    if (n >= N_NODES) return;
    float4 v = *reinterpret_cast<const float4*>(&x[(size_t)n * D + c4]);
    ushort4 o;
    o.x = f2bf(v.x); o.y = f2bf(v.y); o.z = f2bf(v.z); o.w = f2bf(v.w);
    *reinterpret_cast<ushort4*>(&A[(size_t)n * KDIM + D + c4]) = o;
}

// ---------------------------------------------------------------------------
// W (fp32 [K][128]) -> Wt (bf16 [128][256] = [Wl ; Wr] transposed)
// grid: 256 blocks x 128 threads; block = (layer, out-col j)
// ---------------------------------------------------------------------------
__global__ void convert_w(const float* __restrict__ Wl1, const float* __restrict__ Wr1,
                          const float* __restrict__ Wl2, const float* __restrict__ Wr2,
                          unsigned short* __restrict__ Wt1, unsigned short* __restrict__ Wt2) {
    int layer = blockIdx.x >> 7;
    int j = blockIdx.x & 127;
    const float* Wl = layer ? Wl2 : Wl1;
    const float* Wr = layer ? Wr2 : Wr1;
    unsigned short* Wt = layer ? Wt2 : Wt1;
    int k = threadIdx.x;  // 0..127
    Wt[(size_t)j * KDIM + k]     = f2bf(Wl[k * D + j]);
    Wt[(size_t)j * KDIM + D + k] = f2bf(Wr[k * D + j]);
}

// ---------------------------------------------------------------------------
// Mean-aggregate (bf16): one wave per node; lane owns 2 cols (4 B).
// Reads feature rows at A[.][128..255], writes mean to A[.][0..127].
// ---------------------------------------------------------------------------
__global__ void agg_bf16(const unsigned short* __restrict__ A,
                         const int* __restrict__ rowptr,
                         const int* __restrict__ col,
                         unsigned short* __restrict__ out) {
    int wid = (blockIdx.x * blockDim.x + threadIdx.x) >> 6;
    int lane = threadIdx.x & 63;
    if (wid >= N_NODES) return;
    int e0 = rowptr[wid], e1 = rowptr[wid + 1];
    float a0 = 0.f, a1 = 0.f;
    int e = e0;
    for (; e + 1 < e1; e += 2) {
        int s0 = col[e], s1 = col[e + 1];
        unsigned int v0 = *reinterpret_cast<const unsigned int*>(
            &A[(size_t)s0 * KDIM + D + lane * 2]);
        unsigned int v1 = *reinterpret_cast<const unsigned int*>(
            &A[(size_t)s1 * KDIM + D + lane * 2]);
        a0 += bflo(v0) + bflo(v1);
        a1 += bfhi(v0) + bfhi(v1);
    }
    if (e < e1) {
        int s0 = col[e];
        unsigned int v0 = *reinterpret_cast<const unsigned int*>(
            &A[(size_t)s0 * KDIM + D + lane * 2]);
        a0 += bflo(v0);
        a1 += bfhi(v0);
    }
    int deg = e1 - e0;
    float inv = deg > 0 ? 1.0f / (float)deg : 0.0f;
    unsigned int packed =
        ((unsigned int)f2bf(a1 * inv) << 16) | (unsigned int)f2bf(a0 * inv);
    *reinterpret_cast<unsigned int*>(&out[(size_t)wid * KDIM + lane * 2]) = packed;
}

// ---------------------------------------------------------------------------
// MFMA GEMM: out[n][j] = relu( A[n][0..255] . Wt[j][0..255] + bias[j] )
// block = 256 thr = 4 waves; wave w owns 32 output cols; 64 rows per block.
// WRITE_BF16: write h (bf16) into out_bf16[n][128..255] (in-place A, own rows
// only -> no cross-block hazard). Else write fp32 to out_f32[n][0..127].
// ---------------------------------------------------------------------------
template <int WRITE_BF16>
__global__ __launch_bounds__(256)
void sage_gemm(const unsigned short* __restrict__ A,
               const unsigned short* __restrict__ Wt,
               const float* __restrict__ bias,
               float* __restrict__ out_f32,
               unsigned short* __restrict__ out_bf16) {
    const int w = threadIdx.x >> 6;
    const int lane = threadIdx.x & 63;
    const int l16 = lane & 15;
    const int lk = lane >> 4;          // 0..3
    const int row0 = blockIdx.x * 64;
    const int wc = w * 32;             // wave col base

    // B fragments for this wave's 32 cols, all K: loaded once (L2-hot)
    short8 bfrag[2][8];
#pragma unroll
    for (int c = 0; c < 2; ++c)
#pragma unroll
        for (int kk = 0; kk < 8; ++kk)
            bfrag[c][kk] = *reinterpret_cast<const short8*>(
                &Wt[(size_t)(wc + c * 16 + l16) * KDIM + kk * 32 + lk * 8]);

    f32x4 acc[4][2];
#pragma unroll
    for (int r = 0; r < 4; ++r)
#pragma unroll
        for (int c = 0; c < 2; ++c) acc[r][c] = (f32x4)0.0f;

#pragma unroll
    for (int kk = 0; kk < 8; ++kk) {
        short8 af[4];
#pragma unroll
        for (int r = 0; r < 4; ++r) {
            int row = row0 + r * 16 + l16;
            if (row >= N_NODES) row = N_NODES - 1;  // clamp; values unused
            af[r] = *reinterpret_cast<const short8*>(
                &A[(size_t)row * KDIM + kk * 32 + lk * 8]);
        }
#pragma unroll
        for (int r = 0; r < 4; ++r)
#pragma unroll
            for (int c = 0; c < 2; ++c)
                acc[r][c] = __builtin_amdgcn_mfma_f32_16x16x32_bf16(
                    af[r], bfrag[c][kk], acc[r][c], 0, 0, 0);
    }

    // epilogue: C/D layout col=lane&15, row=(lane>>4)*4+reg  [verified m89/m91]
#pragma unroll
    for (int c = 0; c < 2; ++c) {
        int colj = wc + c * 16 + l16;
        float bv = bias[colj];
#pragma unroll
        for (int r = 0; r < 4; ++r) {
#pragma unroll
            for (int q = 0; q < 4; ++q) {
                int row = row0 + r * 16 + lk * 4 + q;
                if (row < N_NODES) {
                    float v = acc[r][c][q] + bv;
                    v = v > 0.f ? v : 0.f;
                    if (WRITE_BF16)
                        out_bf16[(size_t)row * KDIM + D + colj] = f2bf(v);
                    else
                        out_f32[(size_t)row * D + colj] = v;
                }
            }
        }
    }
}

extern "C" void kernel_launch(void* const* d_in, const int* in_sizes, int n_in,
                              void* d_out, int out_size, void* d_ws, size_t ws_size,
                              hipStream_t stream) {
    const float* x   = (const float*)d_in[0];
    const int*   ei  = (const int*)  d_in[1];
    const float* W1l = (const float*)d_in[2];
    const float* b1  = (const float*)d_in[3];
    const float* W1r = (const float*)d_in[4];
    const float* W2l = (const float*)d_in[5];
    const float* b2  = (const float*)d_in[6];
    const float* W2r = (const float*)d_in[7];
    float*       out = (float*)d_out;

    const int n_edges = in_sizes[1] / 2;
    const int* src = ei;
    const int* dst = ei + n_edges;

    // workspace layout (A first for 16B alignment)
    char* ws = (char*)d_ws;
    unsigned short* A   = (unsigned short*)ws;                 // N*256 bf16
    unsigned short* Wt1 = A + (size_t)N_NODES * KDIM;          // 128*256
    unsigned short* Wt2 = Wt1 + 128 * KDIM;                    // 128*256
    int* cnt    = (int*)(Wt2 + 128 * KDIM);                    // N
    int* rowptr = cnt + N_NODES;                               // N+1
    int* cursor = rowptr + (N_NODES + 1);                      // N
    int* col    = cursor + N_NODES;                            // E
    // total ~= 25.6MB + 128KB + 3.2MB

    // ---- CSR build (shared by both layers) ----
    hipMemsetAsync(cnt, 0, N_NODES * sizeof(int), stream);
    hist_kernel<<<(n_edges + 255) / 256, 256, 0, stream>>>(dst, cnt, n_edges);
    scan_kernel<<<1, SCAN_T, 0, stream>>>(cnt, rowptr, cursor);
    scatter_kernel<<<(n_edges + 255) / 256, 256, 0, stream>>>(src, dst, cursor,
                                                              col, n_edges);

    // ---- precision conversion ----
    convert_w<<<256, 128, 0, stream>>>(W1l, W1r, W2l, W2r, Wt1, Wt2);
    convert_x<<<(N_NODES * 32 + 255) / 256, 256, 0, stream>>>(x, A);

    const int gemm_grid = (N_NODES + 63) / 64;

    // ---- layer 1 ----
    agg_bf16<<<(N_NODES * 64 + 255) / 256, 256, 0, stream>>>(A, rowptr, col, A);
    sage_gemm<1><<<gemm_grid, 256, 0, stream>>>(A, Wt1, b1, nullptr, A);

    // ---- layer 2 ----
    agg_bf16<<<(N_NODES * 64 + 255) / 256, 256, 0, stream>>>(A, rowptr, col, A);
    sage_gemm<0><<<gemm_grid, 256, 0, stream>>>(A, Wt2, b2, out, nullptr);
}

// Round 4
// 232.775 us; speedup vs baseline: 6.3818x; 1.5093x over previous
//
#include <hip/hip_runtime.h>

#define N_NODES 50000
#define D 128
#define KDIM 256
#define SCAN_B 256
#define SCAN_NB ((N_NODES + SCAN_B - 1) / SCAN_B)  // 196

typedef __attribute__((ext_vector_type(8))) short short8;
typedef __attribute__((ext_vector_type(4))) float f32x4;

__device__ __forceinline__ unsigned short f2bf(float f) {
    unsigned int u = __builtin_bit_cast(unsigned int, f);
    u += 0x7FFFu + ((u >> 16) & 1u);
    return (unsigned short)(u >> 16);
}
__device__ __forceinline__ float bflo(unsigned int u) {
    return __builtin_bit_cast(float, u << 16);
}
__device__ __forceinline__ float bfhi(unsigned int u) {
    return __builtin_bit_cast(float, u & 0xFFFF0000u);
}

// ---------------------------------------------------------------------------
// CSR build step 1: histogram of dst
// ---------------------------------------------------------------------------
__global__ void hist_kernel(const int* __restrict__ dst,
                            int* __restrict__ cnt, int n_edges) {
    int e = blockIdx.x * blockDim.x + threadIdx.x;
    if (e < n_edges) atomicAdd(&cnt[dst[e]], 1);
}

// ---------------------------------------------------------------------------
// CSR build step 2a: per-block sums of cnt
// ---------------------------------------------------------------------------
__global__ void scan_blocksum(const int* __restrict__ cnt,
                              int* __restrict__ bsum) {
    __shared__ int red[SCAN_B];
    int i = blockIdx.x * SCAN_B + threadIdx.x;
    int v = (i < N_NODES) ? cnt[i] : 0;
    red[threadIdx.x] = v;
    __syncthreads();
    for (int off = SCAN_B / 2; off > 0; off >>= 1) {
        if (threadIdx.x < off) red[threadIdx.x] += red[threadIdx.x + off];
        __syncthreads();
    }
    if (threadIdx.x == 0) bsum[blockIdx.x] = red[0];
}

// ---------------------------------------------------------------------------
// CSR build step 2b: exclusive scan of the 196 block sums (one tiny block)
// ---------------------------------------------------------------------------
__global__ void scan_bsum(const int* __restrict__ bsum,
                          int* __restrict__ bpref,
                          int* __restrict__ rowptr, int n_edges) {
    __shared__ int s[SCAN_B];
    int t = threadIdx.x;
    int v = (t < SCAN_NB) ? bsum[t] : 0;
    s[t] = v;
    __syncthreads();
    for (int off = 1; off < SCAN_B; off <<= 1) {
        int tmp = (t >= off) ? s[t - off] : 0;
        __syncthreads();
        s[t] += tmp;
        __syncthreads();
    }
    if (t < SCAN_NB) bpref[t] = s[t] - v;  // exclusive
    if (t == 0) rowptr[N_NODES] = n_edges; // every dst is in [0,N)
}

// ---------------------------------------------------------------------------
// CSR build step 2c: intra-block exclusive scan + block prefix -> rowptr/cursor
// ---------------------------------------------------------------------------
__global__ void scan_final(const int* __restrict__ cnt,
                           const int* __restrict__ bpref,
                           int* __restrict__ rowptr,
                           int* __restrict__ cursor) {
    __shared__ int s[SCAN_B];
    int t = threadIdx.x;
    int i = blockIdx.x * SCAN_B + t;
    int v = (i < N_NODES) ? cnt[i] : 0;
    s[t] = v;
    __syncthreads();
    for (int off = 1; off < SCAN_B; off <<= 1) {
        int tmp = (t >= off) ? s[t - off] : 0;
        __syncthreads();
        s[t] += tmp;
        __syncthreads();
    }
    if (i < N_NODES) {
        int ex = bpref[blockIdx.x] + s[t] - v;
        rowptr[i] = ex;
        cursor[i] = ex;
    }
}

// ---------------------------------------------------------------------------
// CSR build step 3: scatter src ids into dst-sorted order
// ---------------------------------------------------------------------------
__global__ void scatter_kernel(const int* __restrict__ src,
                               const int* __restrict__ dst,
                               int* __restrict__ cursor,
                               int* __restrict__ col, int n_edges) {
    int e = blockIdx.x * blockDim.x + threadIdx.x;
    if (e < n_edges) {
        int p = atomicAdd(&cursor[dst[e]], 1);
        col[p] = src[e];
    }
}

// ---------------------------------------------------------------------------
// x (fp32) -> A[n][128..255] (bf16)
// ---------------------------------------------------------------------------
__global__ void convert_x(const float* __restrict__ x,
                          unsigned short* __restrict__ A) {
    int t = blockIdx.x * blockDim.x + threadIdx.x;
    int n = t >> 5;             // 32 threads per node row
    int c4 = (t & 31) * 4;
    if (n >= N_NODES) return;
    float4 v = *reinterpret_cast<const float4*>(&x[(size_t)n * D + c4]);
    ushort4 o;
    o.x = f2bf(v.x); o.y = f2bf(v.y); o.z = f2bf(v.z); o.w = f2bf(v.w);
    *reinterpret_cast<ushort4*>(&A[(size_t)n * KDIM + D + c4]) = o;
}

// ---------------------------------------------------------------------------
// W (fp32 [K][128]) -> Wt (bf16 [128][256] = [Wl ; Wr] transposed)
// ---------------------------------------------------------------------------
__global__ void convert_w(const float* __restrict__ Wl1, const float* __restrict__ Wr1,
                          const float* __restrict__ Wl2, const float* __restrict__ Wr2,
                          unsigned short* __restrict__ Wt1, unsigned short* __restrict__ Wt2) {
    int layer = blockIdx.x >> 7;
    int j = blockIdx.x & 127;
    const float* Wl = layer ? Wl2 : Wl1;
    const float* Wr = layer ? Wr2 : Wr1;
    unsigned short* Wt = layer ? Wt2 : Wt1;
    int k = threadIdx.x;  // 0..127
    Wt[(size_t)j * KDIM + k]     = f2bf(Wl[k * D + j]);
    Wt[(size_t)j * KDIM + D + k] = f2bf(Wr[k * D + j]);
}

// ---------------------------------------------------------------------------
// Mean-aggregate (bf16): one wave per node; lane owns 2 cols (4 B).
// Reads feature rows at A[.][128..255], writes mean to A[.][0..127].
// ---------------------------------------------------------------------------
__global__ void agg_bf16(const unsigned short* __restrict__ A,
                         const int* __restrict__ rowptr,
                         const int* __restrict__ col,
                         unsigned short* __restrict__ out) {
    int wid = (blockIdx.x * blockDim.x + threadIdx.x) >> 6;
    int lane = threadIdx.x & 63;
    if (wid >= N_NODES) return;
    int e0 = rowptr[wid], e1 = rowptr[wid + 1];
    float a0 = 0.f, a1 = 0.f;
    int e = e0;
    for (; e + 1 < e1; e += 2) {
        int s0 = col[e], s1 = col[e + 1];
        unsigned int v0 = *reinterpret_cast<const unsigned int*>(
            &A[(size_t)s0 * KDIM + D + lane * 2]);
        unsigned int v1 = *reinterpret_cast<const unsigned int*>(
            &A[(size_t)s1 * KDIM + D + lane * 2]);
        a0 += bflo(v0) + bflo(v1);
        a1 += bfhi(v0) + bfhi(v1);
    }
    if (e < e1) {
        int s0 = col[e];
        unsigned int v0 = *reinterpret_cast<const unsigned int*>(
            &A[(size_t)s0 * KDIM + D + lane * 2]);
        a0 += bflo(v0);
        a1 += bfhi(v0);
    }
    int deg = e1 - e0;
    float inv = deg > 0 ? 1.0f / (float)deg : 0.0f;
    unsigned int packed =
        ((unsigned int)f2bf(a1 * inv) << 16) | (unsigned int)f2bf(a0 * inv);
    *reinterpret_cast<unsigned int*>(&out[(size_t)wid * KDIM + lane * 2]) = packed;
}

// ---------------------------------------------------------------------------
// MFMA GEMM: out[n][j] = relu( A[n][0..255] . Wt[j][0..255] + bias[j] )
// block = 256 thr = 4 waves; wave w owns 32 output cols; 64 rows per block.
// ---------------------------------------------------------------------------
template <int WRITE_BF16>
__global__ __launch_bounds__(256)
void sage_gemm(const unsigned short* __restrict__ A,
               const unsigned short* __restrict__ Wt,
               const float* __restrict__ bias,
               float* __restrict__ out_f32,
               unsigned short* __restrict__ out_bf16) {
    const int w = threadIdx.x >> 6;
    const int lane = threadIdx.x & 63;
    const int l16 = lane & 15;
    const int lk = lane >> 4;          // 0..3
    const int row0 = blockIdx.x * 64;
    const int wc = w * 32;             // wave col base

    short8 bfrag[2][8];
#pragma unroll
    for (int c = 0; c < 2; ++c)
#pragma unroll
        for (int kk = 0; kk < 8; ++kk)
            bfrag[c][kk] = *reinterpret_cast<const short8*>(
                &Wt[(size_t)(wc + c * 16 + l16) * KDIM + kk * 32 + lk * 8]);

    f32x4 acc[4][2];
#pragma unroll
    for (int r = 0; r < 4; ++r)
#pragma unroll
        for (int c = 0; c < 2; ++c) acc[r][c] = (f32x4)0.0f;

#pragma unroll
    for (int kk = 0; kk < 8; ++kk) {
        short8 af[4];
#pragma unroll
        for (int r = 0; r < 4; ++r) {
            int row = row0 + r * 16 + l16;
            if (row >= N_NODES) row = N_NODES - 1;  // clamp; values unused
            af[r] = *reinterpret_cast<const short8*>(
                &A[(size_t)row * KDIM + kk * 32 + lk * 8]);
        }
#pragma unroll
        for (int r = 0; r < 4; ++r)
#pragma unroll
            for (int c = 0; c < 2; ++c)
                acc[r][c] = __builtin_amdgcn_mfma_f32_16x16x32_bf16(
                    af[r], bfrag[c][kk], acc[r][c], 0, 0, 0);
    }

    // epilogue: C/D layout col=lane&15, row=(lane>>4)*4+reg  [verified m89/m91]
#pragma unroll
    for (int c = 0; c < 2; ++c) {
        int colj = wc + c * 16 + l16;
        float bv = bias[colj];
#pragma unroll
        for (int r = 0; r < 4; ++r) {
#pragma unroll
            for (int q = 0; q < 4; ++q) {
                int row = row0 + r * 16 + lk * 4 + q;
                if (row < N_NODES) {
                    float v = acc[r][c][q] + bv;
                    v = v > 0.f ? v : 0.f;
                    if (WRITE_BF16)
                        out_bf16[(size_t)row * KDIM + D + colj] = f2bf(v);
                    else
                        out_f32[(size_t)row * D + colj] = v;
                }
            }
        }
    }
}

extern "C" void kernel_launch(void* const* d_in, const int* in_sizes, int n_in,
                              void* d_out, int out_size, void* d_ws, size_t ws_size,
                              hipStream_t stream) {
    const float* x   = (const float*)d_in[0];
    const int*   ei  = (const int*)  d_in[1];
    const float* W1l = (const float*)d_in[2];
    const float* b1  = (const float*)d_in[3];
    const float* W1r = (const float*)d_in[4];
    const float* W2l = (const float*)d_in[5];
    const float* b2  = (const float*)d_in[6];
    const float* W2r = (const float*)d_in[7];
    float*       out = (float*)d_out;

    const int n_edges = in_sizes[1] / 2;
    const int* src = ei;
    const int* dst = ei + n_edges;

    // workspace layout (A first for 16B alignment)
    char* ws = (char*)d_ws;
    unsigned short* A   = (unsigned short*)ws;                 // N*256 bf16
    unsigned short* Wt1 = A + (size_t)N_NODES * KDIM;          // 128*256
    unsigned short* Wt2 = Wt1 + 128 * KDIM;                    // 128*256
    int* cnt    = (int*)(Wt2 + 128 * KDIM);                    // N
    int* rowptr = cnt + N_NODES;                               // N+1
    int* cursor = rowptr + (N_NODES + 1);                      // N
    int* bsum   = cursor + N_NODES;                            // SCAN_NB
    int* bpref  = bsum + SCAN_NB;                              // SCAN_NB
    int* col    = bpref + SCAN_NB;                             // E

    // ---- CSR build (shared by both layers) ----
    hipMemsetAsync(cnt, 0, N_NODES * sizeof(int), stream);
    hist_kernel<<<(n_edges + 255) / 256, 256, 0, stream>>>(dst, cnt, n_edges);
    scan_blocksum<<<SCAN_NB, SCAN_B, 0, stream>>>(cnt, bsum);
    scan_bsum<<<1, SCAN_B, 0, stream>>>(bsum, bpref, rowptr, n_edges);
    scan_final<<<SCAN_NB, SCAN_B, 0, stream>>>(cnt, bpref, rowptr, cursor);
    scatter_kernel<<<(n_edges + 255) / 256, 256, 0, stream>>>(src, dst, cursor,
                                                              col, n_edges);

    // ---- precision conversion ----
    convert_w<<<256, 128, 0, stream>>>(W1l, W1r, W2l, W2r, Wt1, Wt2);
    convert_x<<<(N_NODES * 32 + 255) / 256, 256, 0, stream>>>(x, A);

    const int gemm_grid = (N_NODES + 63) / 64;

    // ---- layer 1 ----
    agg_bf16<<<(N_NODES * 64 + 255) / 256, 256, 0, stream>>>(A, rowptr, col, A);
    sage_gemm<1><<<gemm_grid, 256, 0, stream>>>(A, Wt1, b1, nullptr, A);

    // ---- layer 2 ----
    agg_bf16<<<(N_NODES * 64 + 255) / 256, 256, 0, stream>>>(A, rowptr, col, A);
    sage_gemm<0><<<gemm_grid, 256, 0, stream>>>(A, Wt2, b2, out, nullptr);
}

// Round 5
// 203.379 us; speedup vs baseline: 7.3042x; 1.1445x over previous
//
#include <hip/hip_runtime.h>

#define N_NODES 50000
#define D 128
#define KDIM 256
#define SCAN_B 256
#define SCAN_NB ((N_NODES + SCAN_B - 1) / SCAN_B)  // 196

typedef __attribute__((ext_vector_type(8))) short short8;
typedef __attribute__((ext_vector_type(4))) float f32x4;

__device__ __forceinline__ unsigned short f2bf(float f) {
    unsigned int u = __builtin_bit_cast(unsigned int, f);
    u += 0x7FFFu + ((u >> 16) & 1u);
    return (unsigned short)(u >> 16);
}
__device__ __forceinline__ float bflo(unsigned int u) {
    return __builtin_bit_cast(float, u << 16);
}
__device__ __forceinline__ float bfhi(unsigned int u) {
    return __builtin_bit_cast(float, u & 0xFFFF0000u);
}

// ---------------------------------------------------------------------------
// CSR build step 1: histogram of dst
// ---------------------------------------------------------------------------
__global__ void hist_kernel(const int* __restrict__ dst,
                            int* __restrict__ cnt, int n_edges) {
    int e = blockIdx.x * blockDim.x + threadIdx.x;
    if (e < n_edges) atomicAdd(&cnt[dst[e]], 1);
}

// ---------------------------------------------------------------------------
// CSR build step 2a: per-block sums of cnt
// ---------------------------------------------------------------------------
__global__ void scan_blocksum(const int* __restrict__ cnt,
                              int* __restrict__ bsum) {
    __shared__ int red[SCAN_B];
    int i = blockIdx.x * SCAN_B + threadIdx.x;
    int v = (i < N_NODES) ? cnt[i] : 0;
    red[threadIdx.x] = v;
    __syncthreads();
    for (int off = SCAN_B / 2; off > 0; off >>= 1) {
        if (threadIdx.x < off) red[threadIdx.x] += red[threadIdx.x + off];
        __syncthreads();
    }
    if (threadIdx.x == 0) bsum[blockIdx.x] = red[0];
}

// ---------------------------------------------------------------------------
// CSR build step 2b: exclusive scan of the 196 block sums (one tiny block)
// ---------------------------------------------------------------------------
__global__ void scan_bsum(const int* __restrict__ bsum,
                          int* __restrict__ bpref,
                          int* __restrict__ rowptr, int n_edges) {
    __shared__ int s[SCAN_B];
    int t = threadIdx.x;
    int v = (t < SCAN_NB) ? bsum[t] : 0;
    s[t] = v;
    __syncthreads();
    for (int off = 1; off < SCAN_B; off <<= 1) {
        int tmp = (t >= off) ? s[t - off] : 0;
        __syncthreads();
        s[t] += tmp;
        __syncthreads();
    }
    if (t < SCAN_NB) bpref[t] = s[t] - v;  // exclusive
    if (t == 0) rowptr[N_NODES] = n_edges; // every dst is in [0,N)
}

// ---------------------------------------------------------------------------
// CSR build step 2c: intra-block exclusive scan + block prefix -> rowptr/cursor
// ---------------------------------------------------------------------------
__global__ void scan_final(const int* __restrict__ cnt,
                           const int* __restrict__ bpref,
                           int* __restrict__ rowptr,
                           int* __restrict__ cursor) {
    __shared__ int s[SCAN_B];
    int t = threadIdx.x;
    int i = blockIdx.x * SCAN_B + t;
    int v = (i < N_NODES) ? cnt[i] : 0;
    s[t] = v;
    __syncthreads();
    for (int off = 1; off < SCAN_B; off <<= 1) {
        int tmp = (t >= off) ? s[t - off] : 0;
        __syncthreads();
        s[t] += tmp;
        __syncthreads();
    }
    if (i < N_NODES) {
        int ex = bpref[blockIdx.x] + s[t] - v;
        rowptr[i] = ex;
        cursor[i] = ex;
    }
}

// ---------------------------------------------------------------------------
// CSR build step 3: scatter src ids into dst-sorted order
// ---------------------------------------------------------------------------
__global__ void scatter_kernel(const int* __restrict__ src,
                               const int* __restrict__ dst,
                               int* __restrict__ cursor,
                               int* __restrict__ col, int n_edges) {
    int e = blockIdx.x * blockDim.x + threadIdx.x;
    if (e < n_edges) {
        int p = atomicAdd(&cursor[dst[e]], 1);
        col[p] = src[e];
    }
}

// ---------------------------------------------------------------------------
// x (fp32) -> A[n][128..255] (bf16)
// ---------------------------------------------------------------------------
__global__ void convert_x(const float* __restrict__ x,
                          unsigned short* __restrict__ A) {
    int t = blockIdx.x * blockDim.x + threadIdx.x;
    int n = t >> 5;             // 32 threads per node row
    int c4 = (t & 31) * 4;
    if (n >= N_NODES) return;
    float4 v = *reinterpret_cast<const float4*>(&x[(size_t)n * D + c4]);
    ushort4 o;
    o.x = f2bf(v.x); o.y = f2bf(v.y); o.z = f2bf(v.z); o.w = f2bf(v.w);
    *reinterpret_cast<ushort4*>(&A[(size_t)n * KDIM + D + c4]) = o;
}

// ---------------------------------------------------------------------------
// W (fp32 [K][128]) -> Wt (bf16 [128][256] = [Wl ; Wr] transposed)
// ---------------------------------------------------------------------------
__global__ void convert_w(const float* __restrict__ Wl1, const float* __restrict__ Wr1,
                          const float* __restrict__ Wl2, const float* __restrict__ Wr2,
                          unsigned short* __restrict__ Wt1, unsigned short* __restrict__ Wt2) {
    int layer = blockIdx.x >> 7;
    int j = blockIdx.x & 127;
    const float* Wl = layer ? Wl2 : Wl1;
    const float* Wr = layer ? Wr2 : Wr1;
    unsigned short* Wt = layer ? Wt2 : Wt1;
    int k = threadIdx.x;  // 0..127
    Wt[(size_t)j * KDIM + k]     = f2bf(Wl[k * D + j]);
    Wt[(size_t)j * KDIM + D + k] = f2bf(Wr[k * D + j]);
}

// ---------------------------------------------------------------------------
// Mean-aggregate (bf16), MLP-optimized:
//  - one wave per node; edge ids loaded cooperatively (one coalesced load)
//  - 4 edges per iteration: quarter-wave (16 lanes x 16B) per gathered row
//  - cross-quarter reduce via __shfl_down(32) then (16); lanes 0-15 store 16B
// Reads feature rows at A[.][128..255], writes mean to out[.][0..127].
// ---------------------------------------------------------------------------
__global__ void agg_bf16(const unsigned short* __restrict__ A,
                         const int* __restrict__ rowptr,
                         const int* __restrict__ col,
                         unsigned short* __restrict__ out) {
    const int wid  = (blockIdx.x * blockDim.x + threadIdx.x) >> 6;
    const int lane = threadIdx.x & 63;
    if (wid >= N_NODES) return;
    const int quarter = lane >> 4;   // 0..3: which edge of the group of 4
    const int l16     = lane & 15;   // 16B chunk within the 256B row

    const int e0  = rowptr[wid];
    const int deg = rowptr[wid + 1] - e0;

    float a[8];
#pragma unroll
    for (int k = 0; k < 8; ++k) a[k] = 0.0f;

    for (int base = 0; base < deg; base += 64) {
        const int nch = min(64, deg - base);
        int myc = (lane < nch) ? col[e0 + base + lane] : 0;

        int i = 0;
        for (; i + 3 < nch; i += 4) {
            const int s = __shfl(myc, i + quarter);
            const uint4 v = *reinterpret_cast<const uint4*>(
                &A[(size_t)s * KDIM + D + l16 * 8]);
            a[0] += bflo(v.x); a[1] += bfhi(v.x);
            a[2] += bflo(v.y); a[3] += bfhi(v.y);
            a[4] += bflo(v.z); a[5] += bfhi(v.z);
            a[6] += bflo(v.w); a[7] += bfhi(v.w);
        }
        if (i < nch) {  // 1-3 leftover edges
            const int idx = i + quarter;
            const int s = __shfl(myc, idx < nch ? idx : nch - 1);
            if (idx < nch) {
                const uint4 v = *reinterpret_cast<const uint4*>(
                    &A[(size_t)s * KDIM + D + l16 * 8]);
                a[0] += bflo(v.x); a[1] += bfhi(v.x);
                a[2] += bflo(v.y); a[3] += bfhi(v.y);
                a[4] += bflo(v.z); a[5] += bfhi(v.z);
                a[6] += bflo(v.w); a[7] += bfhi(v.w);
            }
        }
    }

    // reduce quarters: lane l += lane l+32, then += lane l+16
#pragma unroll
    for (int k = 0; k < 8; ++k) {
        a[k] += __shfl_down(a[k], 32);
        a[k] += __shfl_down(a[k], 16);
    }

    if (lane < 16) {
        const float inv = deg > 0 ? 1.0f / (float)deg : 0.0f;
        uint4 o;
        o.x = ((unsigned int)f2bf(a[1] * inv) << 16) | f2bf(a[0] * inv);
        o.y = ((unsigned int)f2bf(a[3] * inv) << 16) | f2bf(a[2] * inv);
        o.z = ((unsigned int)f2bf(a[5] * inv) << 16) | f2bf(a[4] * inv);
        o.w = ((unsigned int)f2bf(a[7] * inv) << 16) | f2bf(a[6] * inv);
        *reinterpret_cast<uint4*>(&out[(size_t)wid * KDIM + l16 * 8]) = o;
    }
}

// ---------------------------------------------------------------------------
// MFMA GEMM: out[n][j] = relu( A[n][0..255] . Wt[j][0..255] + bias[j] )
// block = 256 thr = 4 waves; wave w owns 32 output cols; 64 rows per block.
// ---------------------------------------------------------------------------
template <int WRITE_BF16>
__global__ __launch_bounds__(256)
void sage_gemm(const unsigned short* __restrict__ A,
               const unsigned short* __restrict__ Wt,
               const float* __restrict__ bias,
               float* __restrict__ out_f32,
               unsigned short* __restrict__ out_bf16) {
    const int w = threadIdx.x >> 6;
    const int lane = threadIdx.x & 63;
    const int l16 = lane & 15;
    const int lk = lane >> 4;          // 0..3
    const int row0 = blockIdx.x * 64;
    const int wc = w * 32;             // wave col base

    short8 bfrag[2][8];
#pragma unroll
    for (int c = 0; c < 2; ++c)
#pragma unroll
        for (int kk = 0; kk < 8; ++kk)
            bfrag[c][kk] = *reinterpret_cast<const short8*>(
                &Wt[(size_t)(wc + c * 16 + l16) * KDIM + kk * 32 + lk * 8]);

    f32x4 acc[4][2];
#pragma unroll
    for (int r = 0; r < 4; ++r)
#pragma unroll
        for (int c = 0; c < 2; ++c) acc[r][c] = (f32x4)0.0f;

#pragma unroll
    for (int kk = 0; kk < 8; ++kk) {
        short8 af[4];
#pragma unroll
        for (int r = 0; r < 4; ++r) {
            int row = row0 + r * 16 + l16;
            if (row >= N_NODES) row = N_NODES - 1;  // clamp; values unused
            af[r] = *reinterpret_cast<const short8*>(
                &A[(size_t)row * KDIM + kk * 32 + lk * 8]);
        }
#pragma unroll
        for (int r = 0; r < 4; ++r)
#pragma unroll
            for (int c = 0; c < 2; ++c)
                acc[r][c] = __builtin_amdgcn_mfma_f32_16x16x32_bf16(
                    af[r], bfrag[c][kk], acc[r][c], 0, 0, 0);
    }

    // epilogue: C/D layout col=lane&15, row=(lane>>4)*4+reg  [verified m89/m91]
#pragma unroll
    for (int c = 0; c < 2; ++c) {
        int colj = wc + c * 16 + l16;
        float bv = bias[colj];
#pragma unroll
        for (int r = 0; r < 4; ++r) {
#pragma unroll
            for (int q = 0; q < 4; ++q) {
                int row = row0 + r * 16 + lk * 4 + q;
                if (row < N_NODES) {
                    float v = acc[r][c][q] + bv;
                    v = v > 0.f ? v : 0.f;
                    if (WRITE_BF16)
                        out_bf16[(size_t)row * KDIM + D + colj] = f2bf(v);
                    else
                        out_f32[(size_t)row * D + colj] = v;
                }
            }
        }
    }
}

extern "C" void kernel_launch(void* const* d_in, const int* in_sizes, int n_in,
                              void* d_out, int out_size, void* d_ws, size_t ws_size,
                              hipStream_t stream) {
    const float* x   = (const float*)d_in[0];
    const int*   ei  = (const int*)  d_in[1];
    const float* W1l = (const float*)d_in[2];
    const float* b1  = (const float*)d_in[3];
    const float* W1r = (const float*)d_in[4];
    const float* W2l = (const float*)d_in[5];
    const float* b2  = (const float*)d_in[6];
    const float* W2r = (const float*)d_in[7];
    float*       out = (float*)d_out;

    const int n_edges = in_sizes[1] / 2;
    const int* src = ei;
    const int* dst = ei + n_edges;

    // workspace layout (A first for 16B alignment)
    char* ws = (char*)d_ws;
    unsigned short* A   = (unsigned short*)ws;                 // N*256 bf16
    unsigned short* Wt1 = A + (size_t)N_NODES * KDIM;          // 128*256
    unsigned short* Wt2 = Wt1 + 128 * KDIM;                    // 128*256
    int* cnt    = (int*)(Wt2 + 128 * KDIM);                    // N
    int* rowptr = cnt + N_NODES;                               // N+1
    int* cursor = rowptr + (N_NODES + 1);                      // N
    int* bsum   = cursor + N_NODES;                            // SCAN_NB
    int* bpref  = bsum + SCAN_NB;                              // SCAN_NB
    int* col    = bpref + SCAN_NB;                             // E

    // ---- CSR build (shared by both layers) ----
    hipMemsetAsync(cnt, 0, N_NODES * sizeof(int), stream);
    hist_kernel<<<(n_edges + 255) / 256, 256, 0, stream>>>(dst, cnt, n_edges);
    scan_blocksum<<<SCAN_NB, SCAN_B, 0, stream>>>(cnt, bsum);
    scan_bsum<<<1, SCAN_B, 0, stream>>>(bsum, bpref, rowptr, n_edges);
    scan_final<<<SCAN_NB, SCAN_B, 0, stream>>>(cnt, bpref, rowptr, cursor);
    scatter_kernel<<<(n_edges + 255) / 256, 256, 0, stream>>>(src, dst, cursor,
                                                              col, n_edges);

    // ---- precision conversion ----
    convert_w<<<256, 128, 0, stream>>>(W1l, W1r, W2l, W2r, Wt1, Wt2);
    convert_x<<<(N_NODES * 32 + 255) / 256, 256, 0, stream>>>(x, A);

    const int gemm_grid = (N_NODES + 63) / 64;

    // ---- layer 1 ----
    agg_bf16<<<(N_NODES * 64 + 255) / 256, 256, 0, stream>>>(A, rowptr, col, A);
    sage_gemm<1><<<gemm_grid, 256, 0, stream>>>(A, Wt1, b1, nullptr, A);

    // ---- layer 2 ----
    agg_bf16<<<(N_NODES * 64 + 255) / 256, 256, 0, stream>>>(A, rowptr, col, A);
    sage_gemm<0><<<gemm_grid, 256, 0, stream>>>(A, Wt2, b2, out, nullptr);
}

// Round 6
// 203.378 us; speedup vs baseline: 7.3042x; 1.0000x over previous
//
#include <hip/hip_runtime.h>

#define N_NODES 50000
#define D 128
#define KDIM 256
#define SCAN_B 256
#define SCAN_NB ((N_NODES + SCAN_B - 1) / SCAN_B)  // 196

typedef __attribute__((ext_vector_type(8))) short short8;
typedef __attribute__((ext_vector_type(4))) float f32x4;

__device__ __forceinline__ unsigned short f2bf(float f) {
    unsigned int u = __builtin_bit_cast(unsigned int, f);
    u += 0x7FFFu + ((u >> 16) & 1u);
    return (unsigned short)(u >> 16);
}
__device__ __forceinline__ float bflo(unsigned int u) {
    return __builtin_bit_cast(float, u << 16);
}
__device__ __forceinline__ float bfhi(unsigned int u) {
    return __builtin_bit_cast(float, u & 0xFFFF0000u);
}

// ---------------------------------------------------------------------------
// zero cnt[] (replaces runtime fillBufferAligned: 41us -> ~3us)
// ---------------------------------------------------------------------------
__global__ void zero_cnt(int* __restrict__ cnt) {
    int i = blockIdx.x * blockDim.x + threadIdx.x;
    if (i < N_NODES) cnt[i] = 0;
}

// ---------------------------------------------------------------------------
// CSR build step 1: histogram of dst
// ---------------------------------------------------------------------------
__global__ void hist_kernel(const int* __restrict__ dst,
                            int* __restrict__ cnt, int n_edges) {
    int e = blockIdx.x * blockDim.x + threadIdx.x;
    if (e < n_edges) atomicAdd(&cnt[dst[e]], 1);
}

// ---------------------------------------------------------------------------
// CSR build step 2a: per-block sums of cnt
// ---------------------------------------------------------------------------
__global__ void scan_blocksum(const int* __restrict__ cnt,
                              int* __restrict__ bsum) {
    __shared__ int red[SCAN_B];
    int i = blockIdx.x * SCAN_B + threadIdx.x;
    int v = (i < N_NODES) ? cnt[i] : 0;
    red[threadIdx.x] = v;
    __syncthreads();
    for (int off = SCAN_B / 2; off > 0; off >>= 1) {
        if (threadIdx.x < off) red[threadIdx.x] += red[threadIdx.x + off];
        __syncthreads();
    }
    if (threadIdx.x == 0) bsum[blockIdx.x] = red[0];
}

// ---------------------------------------------------------------------------
// CSR build step 2b: exclusive scan of the 196 block sums (one tiny block)
// ---------------------------------------------------------------------------
__global__ void scan_bsum(const int* __restrict__ bsum,
                          int* __restrict__ bpref,
                          int* __restrict__ rowptr, int n_edges) {
    __shared__ int s[SCAN_B];
    int t = threadIdx.x;
    int v = (t < SCAN_NB) ? bsum[t] : 0;
    s[t] = v;
    __syncthreads();
    for (int off = 1; off < SCAN_B; off <<= 1) {
        int tmp = (t >= off) ? s[t - off] : 0;
        __syncthreads();
        s[t] += tmp;
        __syncthreads();
    }
    if (t < SCAN_NB) bpref[t] = s[t] - v;  // exclusive
    if (t == 0) rowptr[N_NODES] = n_edges; // every dst is in [0,N)
}

// ---------------------------------------------------------------------------
// CSR build step 2c: intra-block exclusive scan + block prefix -> rowptr/cursor
// ---------------------------------------------------------------------------
__global__ void scan_final(const int* __restrict__ cnt,
                           const int* __restrict__ bpref,
                           int* __restrict__ rowptr,
                           int* __restrict__ cursor) {
    __shared__ int s[SCAN_B];
    int t = threadIdx.x;
    int i = blockIdx.x * SCAN_B + t;
    int v = (i < N_NODES) ? cnt[i] : 0;
    s[t] = v;
    __syncthreads();
    for (int off = 1; off < SCAN_B; off <<= 1) {
        int tmp = (t >= off) ? s[t - off] : 0;
        __syncthreads();
        s[t] += tmp;
        __syncthreads();
    }
    if (i < N_NODES) {
        int ex = bpref[blockIdx.x] + s[t] - v;
        rowptr[i] = ex;
        cursor[i] = ex;
    }
}

// ---------------------------------------------------------------------------
// CSR build step 3: scatter src ids into dst-sorted order
// ---------------------------------------------------------------------------
__global__ void scatter_kernel(const int* __restrict__ src,
                               const int* __restrict__ dst,
                               int* __restrict__ cursor,
                               int* __restrict__ col, int n_edges) {
    int e = blockIdx.x * blockDim.x + threadIdx.x;
    if (e < n_edges) {
        int p = atomicAdd(&cursor[dst[e]], 1);
        col[p] = src[e];
    }
}

// ---------------------------------------------------------------------------
// x (fp32) -> A[n][128..255] (bf16)
// ---------------------------------------------------------------------------
__global__ void convert_x(const float* __restrict__ x,
                          unsigned short* __restrict__ A) {
    int t = blockIdx.x * blockDim.x + threadIdx.x;
    int n = t >> 5;             // 32 threads per node row
    int c4 = (t & 31) * 4;
    if (n >= N_NODES) return;
    float4 v = *reinterpret_cast<const float4*>(&x[(size_t)n * D + c4]);
    ushort4 o;
    o.x = f2bf(v.x); o.y = f2bf(v.y); o.z = f2bf(v.z); o.w = f2bf(v.w);
    *reinterpret_cast<ushort4*>(&A[(size_t)n * KDIM + D + c4]) = o;
}

// ---------------------------------------------------------------------------
// W (fp32 [K][128]) -> Wt (bf16 [128][256] = [Wl ; Wr] transposed)
// ---------------------------------------------------------------------------
__global__ void convert_w(const float* __restrict__ Wl1, const float* __restrict__ Wr1,
                          const float* __restrict__ Wl2, const float* __restrict__ Wr2,
                          unsigned short* __restrict__ Wt1, unsigned short* __restrict__ Wt2) {
    int layer = blockIdx.x >> 7;
    int j = blockIdx.x & 127;
    const float* Wl = layer ? Wl2 : Wl1;
    const float* Wr = layer ? Wr2 : Wr1;
    unsigned short* Wt = layer ? Wt2 : Wt1;
    int k = threadIdx.x;  // 0..127
    Wt[(size_t)j * KDIM + k]     = f2bf(Wl[k * D + j]);
    Wt[(size_t)j * KDIM + D + k] = f2bf(Wr[k * D + j]);
}

// ---------------------------------------------------------------------------
// Mean-aggregate (bf16), MLP-optimized:
//  - one wave per node; edge ids loaded cooperatively (one coalesced load)
//  - 4 edges per iteration: quarter-wave (16 lanes x 16B) per gathered row
//  - cross-quarter reduce via __shfl_down(32) then (16); lanes 0-15 store 16B
// ---------------------------------------------------------------------------
__global__ void agg_bf16(const unsigned short* __restrict__ A,
                         const int* __restrict__ rowptr,
                         const int* __restrict__ col,
                         unsigned short* __restrict__ out) {
    const int wid  = (blockIdx.x * blockDim.x + threadIdx.x) >> 6;
    const int lane = threadIdx.x & 63;
    if (wid >= N_NODES) return;
    const int quarter = lane >> 4;   // 0..3: which edge of the group of 4
    const int l16     = lane & 15;   // 16B chunk within the 256B row

    const int e0  = rowptr[wid];
    const int deg = rowptr[wid + 1] - e0;

    float a[8];
#pragma unroll
    for (int k = 0; k < 8; ++k) a[k] = 0.0f;

    for (int base = 0; base < deg; base += 64) {
        const int nch = min(64, deg - base);
        int myc = (lane < nch) ? col[e0 + base + lane] : 0;

        int i = 0;
        for (; i + 3 < nch; i += 4) {
            const int s = __shfl(myc, i + quarter);
            const uint4 v = *reinterpret_cast<const uint4*>(
                &A[(size_t)s * KDIM + D + l16 * 8]);
            a[0] += bflo(v.x); a[1] += bfhi(v.x);
            a[2] += bflo(v.y); a[3] += bfhi(v.y);
            a[4] += bflo(v.z); a[5] += bfhi(v.z);
            a[6] += bflo(v.w); a[7] += bfhi(v.w);
        }
        if (i < nch) {  // 1-3 leftover edges
            const int idx = i + quarter;
            const int s = __shfl(myc, idx < nch ? idx : nch - 1);
            if (idx < nch) {
                const uint4 v = *reinterpret_cast<const uint4*>(
                    &A[(size_t)s * KDIM + D + l16 * 8]);
                a[0] += bflo(v.x); a[1] += bfhi(v.x);
                a[2] += bflo(v.y); a[3] += bfhi(v.y);
                a[4] += bflo(v.z); a[5] += bfhi(v.z);
                a[6] += bflo(v.w); a[7] += bfhi(v.w);
            }
        }
    }

#pragma unroll
    for (int k = 0; k < 8; ++k) {
        a[k] += __shfl_down(a[k], 32);
        a[k] += __shfl_down(a[k], 16);
    }

    if (lane < 16) {
        const float inv = deg > 0 ? 1.0f / (float)deg : 0.0f;
        uint4 o;
        o.x = ((unsigned int)f2bf(a[1] * inv) << 16) | f2bf(a[0] * inv);
        o.y = ((unsigned int)f2bf(a[3] * inv) << 16) | f2bf(a[2] * inv);
        o.z = ((unsigned int)f2bf(a[5] * inv) << 16) | f2bf(a[4] * inv);
        o.w = ((unsigned int)f2bf(a[7] * inv) << 16) | f2bf(a[6] * inv);
        *reinterpret_cast<uint4*>(&out[(size_t)wid * KDIM + l16 * 8]) = o;
    }
}

// ---------------------------------------------------------------------------
// MFMA GEMM: out[n][j] = relu( A[n][0..255] . Wt[j][0..255] + bias[j] )
// block = 256 thr = 4 waves; wave w owns 32 output cols; 64 rows per block.
// ---------------------------------------------------------------------------
template <int WRITE_BF16>
__global__ __launch_bounds__(256)
void sage_gemm(const unsigned short* __restrict__ A,
               const unsigned short* __restrict__ Wt,
               const float* __restrict__ bias,
               float* __restrict__ out_f32,
               unsigned short* __restrict__ out_bf16) {
    const int w = threadIdx.x >> 6;
    const int lane = threadIdx.x & 63;
    const int l16 = lane & 15;
    const int lk = lane >> 4;          // 0..3
    const int row0 = blockIdx.x * 64;
    const int wc = w * 32;             // wave col base

    short8 bfrag[2][8];
#pragma unroll
    for (int c = 0; c < 2; ++c)
#pragma unroll
        for (int kk = 0; kk < 8; ++kk)
            bfrag[c][kk] = *reinterpret_cast<const short8*>(
                &Wt[(size_t)(wc + c * 16 + l16) * KDIM + kk * 32 + lk * 8]);

    f32x4 acc[4][2];
#pragma unroll
    for (int r = 0; r < 4; ++r)
#pragma unroll
        for (int c = 0; c < 2; ++c) acc[r][c] = (f32x4)0.0f;

#pragma unroll
    for (int kk = 0; kk < 8; ++kk) {
        short8 af[4];
#pragma unroll
        for (int r = 0; r < 4; ++r) {
            int row = row0 + r * 16 + l16;
            if (row >= N_NODES) row = N_NODES - 1;  // clamp; values unused
            af[r] = *reinterpret_cast<const short8*>(
                &A[(size_t)row * KDIM + kk * 32 + lk * 8]);
        }
#pragma unroll
        for (int r = 0; r < 4; ++r)
#pragma unroll
            for (int c = 0; c < 2; ++c)
                acc[r][c] = __builtin_amdgcn_mfma_f32_16x16x32_bf16(
                    af[r], bfrag[c][kk], acc[r][c], 0, 0, 0);
    }

    // epilogue: C/D layout col=lane&15, row=(lane>>4)*4+reg  [verified m89/m91]
#pragma unroll
    for (int c = 0; c < 2; ++c) {
        int colj = wc + c * 16 + l16;
        float bv = bias[colj];
#pragma unroll
        for (int r = 0; r < 4; ++r) {
#pragma unroll
            for (int q = 0; q < 4; ++q) {
                int row = row0 + r * 16 + lk * 4 + q;
                if (row < N_NODES) {
                    float v = acc[r][c][q] + bv;
                    v = v > 0.f ? v : 0.f;
                    if (WRITE_BF16)
                        out_bf16[(size_t)row * KDIM + D + colj] = f2bf(v);
                    else
                        out_f32[(size_t)row * D + colj] = v;
                }
            }
        }
    }
}

extern "C" void kernel_launch(void* const* d_in, const int* in_sizes, int n_in,
                              void* d_out, int out_size, void* d_ws, size_t ws_size,
                              hipStream_t stream) {
    const float* x   = (const float*)d_in[0];
    const int*   ei  = (const int*)  d_in[1];
    const float* W1l = (const float*)d_in[2];
    const float* b1  = (const float*)d_in[3];
    const float* W1r = (const float*)d_in[4];
    const float* W2l = (const float*)d_in[5];
    const float* b2  = (const float*)d_in[6];
    const float* W2r = (const float*)d_in[7];
    float*       out = (float*)d_out;

    const int n_edges = in_sizes[1] / 2;
    const int* src = ei;
    const int* dst = ei + n_edges;

    // workspace layout (A first for 16B alignment)
    char* ws = (char*)d_ws;
    unsigned short* A   = (unsigned short*)ws;                 // N*256 bf16
    unsigned short* Wt1 = A + (size_t)N_NODES * KDIM;          // 128*256
    unsigned short* Wt2 = Wt1 + 128 * KDIM;                    // 128*256
    int* cnt    = (int*)(Wt2 + 128 * KDIM);                    // N
    int* rowptr = cnt + N_NODES;                               // N+1
    int* cursor = rowptr + (N_NODES + 1);                      // N
    int* bsum   = cursor + N_NODES;                            // SCAN_NB
    int* bpref  = bsum + SCAN_NB;                              // SCAN_NB
    int* col    = bpref + SCAN_NB;                             // E

    // ---- CSR build (shared by both layers) ----
    zero_cnt<<<SCAN_NB, SCAN_B, 0, stream>>>(cnt);
    hist_kernel<<<(n_edges + 255) / 256, 256, 0, stream>>>(dst, cnt, n_edges);
    scan_blocksum<<<SCAN_NB, SCAN_B, 0, stream>>>(cnt, bsum);
    scan_bsum<<<1, SCAN_B, 0, stream>>>(bsum, bpref, rowptr, n_edges);
    scan_final<<<SCAN_NB, SCAN_B, 0, stream>>>(cnt, bpref, rowptr, cursor);
    scatter_kernel<<<(n_edges + 255) / 256, 256, 0, stream>>>(src, dst, cursor,
                                                              col, n_edges);

    // ---- precision conversion ----
    convert_w<<<256, 128, 0, stream>>>(W1l, W1r, W2l, W2r, Wt1, Wt2);
    convert_x<<<(N_NODES * 32 + 255) / 256, 256, 0, stream>>>(x, A);

    const int gemm_grid = (N_NODES + 63) / 64;

    // ---- layer 1 ----
    agg_bf16<<<(N_NODES * 64 + 255) / 256, 256, 0, stream>>>(A, rowptr, col, A);
    sage_gemm<1><<<gemm_grid, 256, 0, stream>>>(A, Wt1, b1, nullptr, A);

    // ---- layer 2 ----
    agg_bf16<<<(N_NODES * 64 + 255) / 256, 256, 0, stream>>>(A, rowptr, col, A);
    sage_gemm<0><<<gemm_grid, 256, 0, stream>>>(A, Wt2, b2, out, nullptr);
}

// Round 7
// 197.605 us; speedup vs baseline: 7.5176x; 1.0292x over previous
//
#include <hip/hip_runtime.h>

#define N_NODES 50000
#define D 128
#define KDIM 256
#define SCAN_B 256
#define SCAN_NB ((N_NODES + SCAN_B - 1) / SCAN_B)  // 196
#define CW_NB 256                                   // convert_w blocks
#define CX_NB ((N_NODES * 32) / 256)                // 6250 convert_x blocks

typedef __attribute__((ext_vector_type(8))) short short8;
typedef __attribute__((ext_vector_type(4))) float f32x4;

__device__ __forceinline__ unsigned short f2bf(float f) {
    unsigned int u = __builtin_bit_cast(unsigned int, f);
    u += 0x7FFFu + ((u >> 16) & 1u);
    return (unsigned short)(u >> 16);
}
__device__ __forceinline__ float bflo(unsigned int u) {
    return __builtin_bit_cast(float, u << 16);
}
__device__ __forceinline__ float bfhi(unsigned int u) {
    return __builtin_bit_cast(float, u & 0xFFFF0000u);
}

// ---------------------------------------------------------------------------
// prep: fused {zero cnt+flags | convert W | convert x}, branch per block range
// blocks [0,196): zero cnt + bflag; [196,452): convert_w; [452,6702): convert_x
// ---------------------------------------------------------------------------
__global__ void prep_kernel(int* __restrict__ cnt, int* __restrict__ bflag,
                            const float* __restrict__ Wl1, const float* __restrict__ Wr1,
                            const float* __restrict__ Wl2, const float* __restrict__ Wr2,
                            unsigned short* __restrict__ Wt1, unsigned short* __restrict__ Wt2,
                            const float* __restrict__ x, unsigned short* __restrict__ A) {
    const int bid = blockIdx.x;
    const int t = threadIdx.x;
    if (bid < SCAN_NB) {
        int i = bid * SCAN_B + t;
        if (i < N_NODES) cnt[i] = 0;
        if (t == 0) bflag[bid] = 0;
    } else if (bid < SCAN_NB + CW_NB) {
        if (t < 128) {
            int wb = bid - SCAN_NB;
            int layer = wb >> 7;
            int j = wb & 127;
            const float* Wl = layer ? Wl2 : Wl1;
            const float* Wr = layer ? Wr2 : Wr1;
            unsigned short* Wt = layer ? Wt2 : Wt1;
            Wt[(size_t)j * KDIM + t]     = f2bf(Wl[t * D + j]);
            Wt[(size_t)j * KDIM + D + t] = f2bf(Wr[t * D + j]);
        }
    } else {
        int g = (bid - SCAN_NB - CW_NB) * 256 + t;
        int n = g >> 5;
        int c4 = (g & 31) * 4;
        if (n < N_NODES) {
            float4 v = *reinterpret_cast<const float4*>(&x[(size_t)n * D + c4]);
            ushort4 o;
            o.x = f2bf(v.x); o.y = f2bf(v.y); o.z = f2bf(v.z); o.w = f2bf(v.w);
            *reinterpret_cast<ushort4*>(&A[(size_t)n * KDIM + D + c4]) = o;
        }
    }
}

// ---------------------------------------------------------------------------
// CSR build step 1: histogram of dst
// ---------------------------------------------------------------------------
__global__ void hist_kernel(const int* __restrict__ dst,
                            int* __restrict__ cnt, int n_edges) {
    int e = blockIdx.x * blockDim.x + threadIdx.x;
    if (e < n_edges) atomicAdd(&cnt[dst[e]], 1);
}

// ---------------------------------------------------------------------------
// CSR build step 2: single-pass exclusive scan (decoupled lookback, aggregate
// flags only). 196 blocks, all co-resident (<=256 CUs) -> no deadlock; exact
// scan -> deterministic output. bflag zeroed by prep each call.
// ---------------------------------------------------------------------------
__global__ __launch_bounds__(SCAN_B)
void scan_lookback(const int* __restrict__ cnt,
                   int* __restrict__ rowptr,
                   int* __restrict__ cursor,
                   int* __restrict__ bagg,
                   int* __restrict__ bflag, int n_edges) {
    __shared__ int s[SCAN_B];
    __shared__ int sh_prefix;
    const int bid = blockIdx.x;
    const int t = threadIdx.x;
    const int i = bid * SCAN_B + t;
    const int v = (i < N_NODES) ? cnt[i] : 0;
    s[t] = v;
    __syncthreads();
    for (int off = 1; off < SCAN_B; off <<= 1) {
        int tmp = (t >= off) ? s[t - off] : 0;
        __syncthreads();
        s[t] += tmp;
        __syncthreads();
    }
    // publish this block's aggregate (release orders the bagg store)
    if (t == 0) {
        bagg[bid] = s[SCAN_B - 1];
        __hip_atomic_store(&bflag[bid], 1, __ATOMIC_RELEASE,
                           __HIP_MEMORY_SCOPE_AGENT);
        sh_prefix = 0;
        if (bid == 0) rowptr[N_NODES] = n_edges;  // every dst in [0,N)
    }
    // wave-parallel lookback over predecessors
    if (bid > 0 && t < 64) {
        int part = 0;
        for (int j = t; j < bid; j += 64) {
            while (__hip_atomic_load(&bflag[j], __ATOMIC_ACQUIRE,
                                     __HIP_MEMORY_SCOPE_AGENT) == 0) {}
            part += bagg[j];
        }
#pragma unroll
        for (int off = 32; off > 0; off >>= 1) part += __shfl_down(part, off);
        if (t == 0) sh_prefix = part;
    }
    __syncthreads();
    if (i < N_NODES) {
        int ex = sh_prefix + s[t] - v;  // exclusive global prefix
        rowptr[i] = ex;
        cursor[i] = ex;
    }
}

// ---------------------------------------------------------------------------
// CSR build step 3: scatter src ids into dst-sorted order
// ---------------------------------------------------------------------------
__global__ void scatter_kernel(const int* __restrict__ src,
                               const int* __restrict__ dst,
                               int* __restrict__ cursor,
                               int* __restrict__ col, int n_edges) {
    int e = blockIdx.x * blockDim.x + threadIdx.x;
    if (e < n_edges) {
        int p = atomicAdd(&cursor[dst[e]], 1);
        col[p] = src[e];
    }
}

// ---------------------------------------------------------------------------
// Mean-aggregate (bf16), MLP-optimized:
//  - one wave per node; edge ids loaded cooperatively (one coalesced load)
//  - main loop: 8 edges/iter (2 independent uint4 gathers per quarter-wave,
//    8 row-loads in flight); then 4-edge step; then 1-3 tail
//  - cross-quarter reduce via __shfl_down(32)+(16); lanes 0-15 store 16B
// ---------------------------------------------------------------------------
__global__ void agg_bf16(const unsigned short* __restrict__ A,
                         const int* __restrict__ rowptr,
                         const int* __restrict__ col,
                         unsigned short* __restrict__ out) {
    const int wid  = (blockIdx.x * blockDim.x + threadIdx.x) >> 6;
    const int lane = threadIdx.x & 63;
    if (wid >= N_NODES) return;
    const int quarter = lane >> 4;
    const int l16     = lane & 15;

    const int e0  = rowptr[wid];
    const int deg = rowptr[wid + 1] - e0;

    float a[8];
#pragma unroll
    for (int k = 0; k < 8; ++k) a[k] = 0.0f;

    for (int base = 0; base < deg; base += 64) {
        const int nch = min(64, deg - base);
        int myc = (lane < nch) ? col[e0 + base + lane] : 0;

        int i = 0;
        for (; i + 7 < nch; i += 8) {
            const int s0 = __shfl(myc, i + quarter);
            const int s1 = __shfl(myc, i + 4 + quarter);
            const uint4 v0 = *reinterpret_cast<const uint4*>(
                &A[(size_t)s0 * KDIM + D + l16 * 8]);
            const uint4 v1 = *reinterpret_cast<const uint4*>(
                &A[(size_t)s1 * KDIM + D + l16 * 8]);
            a[0] += bflo(v0.x) + bflo(v1.x); a[1] += bfhi(v0.x) + bfhi(v1.x);
            a[2] += bflo(v0.y) + bflo(v1.y); a[3] += bfhi(v0.y) + bfhi(v1.y);
            a[4] += bflo(v0.z) + bflo(v1.z); a[5] += bfhi(v0.z) + bfhi(v1.z);
            a[6] += bflo(v0.w) + bflo(v1.w); a[7] += bfhi(v0.w) + bfhi(v1.w);
        }
        for (; i + 3 < nch; i += 4) {
            const int s = __shfl(myc, i + quarter);
            const uint4 v = *reinterpret_cast<const uint4*>(
                &A[(size_t)s * KDIM + D + l16 * 8]);
            a[0] += bflo(v.x); a[1] += bfhi(v.x);
            a[2] += bflo(v.y); a[3] += bfhi(v.y);
            a[4] += bflo(v.z); a[5] += bfhi(v.z);
            a[6] += bflo(v.w); a[7] += bfhi(v.w);
        }
        if (i < nch) {  // 1-3 leftover edges
            const int idx = i + quarter;
            const int s = __shfl(myc, idx < nch ? idx : nch - 1);
            if (idx < nch) {
                const uint4 v = *reinterpret_cast<const uint4*>(
                    &A[(size_t)s * KDIM + D + l16 * 8]);
                a[0] += bflo(v.x); a[1] += bfhi(v.x);
                a[2] += bflo(v.y); a[3] += bfhi(v.y);
                a[4] += bflo(v.z); a[5] += bfhi(v.z);
                a[6] += bflo(v.w); a[7] += bfhi(v.w);
            }
        }
    }

#pragma unroll
    for (int k = 0; k < 8; ++k) {
        a[k] += __shfl_down(a[k], 32);
        a[k] += __shfl_down(a[k], 16);
    }

    if (lane < 16) {
        const float inv = deg > 0 ? 1.0f / (float)deg : 0.0f;
        uint4 o;
        o.x = ((unsigned int)f2bf(a[1] * inv) << 16) | f2bf(a[0] * inv);
        o.y = ((unsigned int)f2bf(a[3] * inv) << 16) | f2bf(a[2] * inv);
        o.z = ((unsigned int)f2bf(a[5] * inv) << 16) | f2bf(a[4] * inv);
        o.w = ((unsigned int)f2bf(a[7] * inv) << 16) | f2bf(a[6] * inv);
        *reinterpret_cast<uint4*>(&out[(size_t)wid * KDIM + l16 * 8]) = o;
    }
}

// ---------------------------------------------------------------------------
// MFMA GEMM: out[n][j] = relu( A[n][0..255] . Wt[j][0..255] + bias[j] )
// block = 256 thr = 4 waves; wave w owns 32 output cols; 64 rows per block.
// ---------------------------------------------------------------------------
template <int WRITE_BF16>
__global__ __launch_bounds__(256)
void sage_gemm(const unsigned short* __restrict__ A,
               const unsigned short* __restrict__ Wt,
               const float* __restrict__ bias,
               float* __restrict__ out_f32,
               unsigned short* __restrict__ out_bf16) {
    const int w = threadIdx.x >> 6;
    const int lane = threadIdx.x & 63;
    const int l16 = lane & 15;
    const int lk = lane >> 4;          // 0..3
    const int row0 = blockIdx.x * 64;
    const int wc = w * 32;             // wave col base

    short8 bfrag[2][8];
#pragma unroll
    for (int c = 0; c < 2; ++c)
#pragma unroll
        for (int kk = 0; kk < 8; ++kk)
            bfrag[c][kk] = *reinterpret_cast<const short8*>(
                &Wt[(size_t)(wc + c * 16 + l16) * KDIM + kk * 32 + lk * 8]);

    f32x4 acc[4][2];
#pragma unroll
    for (int r = 0; r < 4; ++r)
#pragma unroll
        for (int c = 0; c < 2; ++c) acc[r][c] = (f32x4)0.0f;

#pragma unroll
    for (int kk = 0; kk < 8; ++kk) {
        short8 af[4];
#pragma unroll
        for (int r = 0; r < 4; ++r) {
            int row = row0 + r * 16 + l16;
            if (row >= N_NODES) row = N_NODES - 1;  // clamp; values unused
            af[r] = *reinterpret_cast<const short8*>(
                &A[(size_t)row * KDIM + kk * 32 + lk * 8]);
        }
#pragma unroll
        for (int r = 0; r < 4; ++r)
#pragma unroll
            for (int c = 0; c < 2; ++c)
                acc[r][c] = __builtin_amdgcn_mfma_f32_16x16x32_bf16(
                    af[r], bfrag[c][kk], acc[r][c], 0, 0, 0);
    }

    // epilogue: C/D layout col=lane&15, row=(lane>>4)*4+reg  [verified m89/m91]
#pragma unroll
    for (int c = 0; c < 2; ++c) {
        int colj = wc + c * 16 + l16;
        float bv = bias[colj];
#pragma unroll
        for (int r = 0; r < 4; ++r) {
#pragma unroll
            for (int q = 0; q < 4; ++q) {
                int row = row0 + r * 16 + lk * 4 + q;
                if (row < N_NODES) {
                    float v = acc[r][c][q] + bv;
                    v = v > 0.f ? v : 0.f;
                    if (WRITE_BF16)
                        out_bf16[(size_t)row * KDIM + D + colj] = f2bf(v);
                    else
                        out_f32[(size_t)row * D + colj] = v;
                }
            }
        }
    }
}

extern "C" void kernel_launch(void* const* d_in, const int* in_sizes, int n_in,
                              void* d_out, int out_size, void* d_ws, size_t ws_size,
                              hipStream_t stream) {
    const float* x   = (const float*)d_in[0];
    const int*   ei  = (const int*)  d_in[1];
    const float* W1l = (const float*)d_in[2];
    const float* b1  = (const float*)d_in[3];
    const float* W1r = (const float*)d_in[4];
    const float* W2l = (const float*)d_in[5];
    const float* b2  = (const float*)d_in[6];
    const float* W2r = (const float*)d_in[7];
    float*       out = (float*)d_out;

    const int n_edges = in_sizes[1] / 2;
    const int* src = ei;
    const int* dst = ei + n_edges;

    // workspace layout (A first for 16B alignment)
    char* ws = (char*)d_ws;
    unsigned short* A   = (unsigned short*)ws;                 // N*256 bf16
    unsigned short* Wt1 = A + (size_t)N_NODES * KDIM;          // 128*256
    unsigned short* Wt2 = Wt1 + 128 * KDIM;                    // 128*256
    int* cnt    = (int*)(Wt2 + 128 * KDIM);                    // N
    int* rowptr = cnt + N_NODES;                               // N+1
    int* cursor = rowptr + (N_NODES + 1);                      // N
    int* bagg   = cursor + N_NODES;                            // SCAN_NB
    int* bflag  = bagg + SCAN_NB;                              // SCAN_NB
    int* col    = bflag + SCAN_NB;                             // E

    // ---- prep: zero cnt/flags + convert W + convert x (1 launch) ----
    prep_kernel<<<SCAN_NB + CW_NB + CX_NB, 256, 0, stream>>>(
        cnt, bflag, W1l, W1r, W2l, W2r, Wt1, Wt2, x, A);

    // ---- CSR build: hist -> single-pass scan -> scatter ----
    hist_kernel<<<(n_edges + 255) / 256, 256, 0, stream>>>(dst, cnt, n_edges);
    scan_lookback<<<SCAN_NB, SCAN_B, 0, stream>>>(cnt, rowptr, cursor, bagg,
                                                  bflag, n_edges);
    scatter_kernel<<<(n_edges + 255) / 256, 256, 0, stream>>>(src, dst, cursor,
                                                              col, n_edges);

    const int gemm_grid = (N_NODES + 63) / 64;

    // ---- layer 1 ----
    agg_bf16<<<(N_NODES * 64 + 255) / 256, 256, 0, stream>>>(A, rowptr, col, A);
    sage_gemm<1><<<gemm_grid, 256, 0, stream>>>(A, Wt1, b1, nullptr, A);

    // ---- layer 2 ----
    agg_bf16<<<(N_NODES * 64 + 255) / 256, 256, 0, stream>>>(A, rowptr, col, A);
    sage_gemm<0><<<gemm_grid, 256, 0, stream>>>(A, Wt2, b2, out, nullptr);
}

// Round 8
// 191.724 us; speedup vs baseline: 7.7482x; 1.0307x over previous
//
#include <hip/hip_runtime.h>

#define N_NODES 50000
#define D 128
#define KDIM 256
#define SCAN_B 256
#define SCAN_NB ((N_NODES + SCAN_B - 1) / SCAN_B)  // 196
#define CW_NB 256                                   // convert_w blocks
#define CX_NB ((N_NODES * 32) / 256)                // 6250 convert_x blocks
#define NR 8                                        // XCD bins
#define RNG ((N_NODES + NR - 1) / NR)               // 6250 nodes per bin
#define SC_CHUNK 4096                               // edges per scatter chunk

typedef __attribute__((ext_vector_type(8))) short short8;
typedef __attribute__((ext_vector_type(4))) float f32x4;

__device__ __forceinline__ unsigned short f2bf(float f) {
    unsigned int u = __builtin_bit_cast(unsigned int, f);
    u += 0x7FFFu + ((u >> 16) & 1u);
    return (unsigned short)(u >> 16);
}
__device__ __forceinline__ float bflo(unsigned int u) {
    return __builtin_bit_cast(float, u << 16);
}
__device__ __forceinline__ float bfhi(unsigned int u) {
    return __builtin_bit_cast(float, u & 0xFFFF0000u);
}

// ---------------------------------------------------------------------------
// prep: fused {zero cnt+flags | convert W | convert x}, branch per block range
// ---------------------------------------------------------------------------
__global__ void prep_kernel(int* __restrict__ cnt, int* __restrict__ bflag,
                            const float* __restrict__ Wl1, const float* __restrict__ Wr1,
                            const float* __restrict__ Wl2, const float* __restrict__ Wr2,
                            unsigned short* __restrict__ Wt1, unsigned short* __restrict__ Wt2,
                            const float* __restrict__ x, unsigned short* __restrict__ A) {
    const int bid = blockIdx.x;
    const int t = threadIdx.x;
    if (bid < SCAN_NB) {
        int i = bid * SCAN_B + t;
        if (i < N_NODES) cnt[i] = 0;
        if (t == 0) bflag[bid] = 0;
    } else if (bid < SCAN_NB + CW_NB) {
        if (t < 128) {
            int wb = bid - SCAN_NB;
            int layer = wb >> 7;
            int j = wb & 127;
            const float* Wl = layer ? Wl2 : Wl1;
            const float* Wr = layer ? Wr2 : Wr1;
            unsigned short* Wt = layer ? Wt2 : Wt1;
            Wt[(size_t)j * KDIM + t]     = f2bf(Wl[t * D + j]);
            Wt[(size_t)j * KDIM + D + t] = f2bf(Wr[t * D + j]);
        }
    } else {
        int g = (bid - SCAN_NB - CW_NB) * 256 + t;
        int n = g >> 5;
        int c4 = (g & 31) * 4;
        if (n < N_NODES) {
            float4 v = *reinterpret_cast<const float4*>(&x[(size_t)n * D + c4]);
            ushort4 o;
            o.x = f2bf(v.x); o.y = f2bf(v.y); o.z = f2bf(v.z); o.w = f2bf(v.w);
            *reinterpret_cast<ushort4*>(&A[(size_t)n * KDIM + D + c4]) = o;
        }
    }
}

// ---------------------------------------------------------------------------
// CSR build step 1: histogram of dst
// ---------------------------------------------------------------------------
__global__ void hist_kernel(const int* __restrict__ dst,
                            int* __restrict__ cnt, int n_edges) {
    int e = blockIdx.x * blockDim.x + threadIdx.x;
    if (e < n_edges) atomicAdd(&cnt[dst[e]], 1);
}

// ---------------------------------------------------------------------------
// CSR build step 2: single-pass exclusive scan (decoupled lookback)
// ---------------------------------------------------------------------------
__global__ __launch_bounds__(SCAN_B)
void scan_lookback(const int* __restrict__ cnt,
                   int* __restrict__ rowptr,
                   int* __restrict__ cursor,
                   int* __restrict__ bagg,
                   int* __restrict__ bflag, int n_edges) {
    __shared__ int s[SCAN_B];
    __shared__ int sh_prefix;
    const int bid = blockIdx.x;
    const int t = threadIdx.x;
    const int i = bid * SCAN_B + t;
    const int v = (i < N_NODES) ? cnt[i] : 0;
    s[t] = v;
    __syncthreads();
    for (int off = 1; off < SCAN_B; off <<= 1) {
        int tmp = (t >= off) ? s[t - off] : 0;
        __syncthreads();
        s[t] += tmp;
        __syncthreads();
    }
    if (t == 0) {
        bagg[bid] = s[SCAN_B - 1];
        __hip_atomic_store(&bflag[bid], 1, __ATOMIC_RELEASE,
                           __HIP_MEMORY_SCOPE_AGENT);
        sh_prefix = 0;
        if (bid == 0) rowptr[N_NODES] = n_edges;  // every dst in [0,N)
    }
    if (bid > 0 && t < 64) {
        int part = 0;
        for (int j = t; j < bid; j += 64) {
            while (__hip_atomic_load(&bflag[j], __ATOMIC_ACQUIRE,
                                     __HIP_MEMORY_SCOPE_AGENT) == 0) {}
            part += bagg[j];
        }
#pragma unroll
        for (int off = 32; off > 0; off >>= 1) part += __shfl_down(part, off);
        if (t == 0) sh_prefix = part;
    }
    __syncthreads();
    if (i < N_NODES) {
        int ex = sh_prefix + s[t] - v;
        rowptr[i] = ex;
        cursor[i] = ex;
    }
}

// ---------------------------------------------------------------------------
// CSR build step 3: XCD-binned scatter. Block b: dst range (b&7), edge chunk
// (b>>3). Round-robin blockIdx->XCD puts each dst range's col slice (~320KB)
// in one XCD L2 -> full-line writebacks instead of 16x-amplified 4B stores.
// ---------------------------------------------------------------------------
__global__ void scatter_binned(const int* __restrict__ src,
                               const int* __restrict__ dst,
                               int* __restrict__ cursor,
                               int* __restrict__ col, int n_edges) {
    const int r = blockIdx.x & (NR - 1);
    const int c = blockIdx.x >> 3;
    const int lo = r * RNG;
    const int hi = min(N_NODES, lo + RNG);
    const int ebase = c * SC_CHUNK;
    const int eend = min(n_edges, ebase + SC_CHUNK);
    for (int e = ebase + threadIdx.x; e < eend; e += 256) {
        int d = dst[e];
        if (d >= lo && d < hi) {
            int p = atomicAdd(&cursor[d], 1);
            col[p] = src[e];
        }
    }
}

// ---------------------------------------------------------------------------
// Mean-aggregate (bf16): one wave/node, cooperative index load, 8 edges/iter
// ---------------------------------------------------------------------------
__global__ void agg_bf16(const unsigned short* __restrict__ A,
                         const int* __restrict__ rowptr,
                         const int* __restrict__ col,
                         unsigned short* __restrict__ out) {
    const int wid  = (blockIdx.x * blockDim.x + threadIdx.x) >> 6;
    const int lane = threadIdx.x & 63;
    if (wid >= N_NODES) return;
    const int quarter = lane >> 4;
    const int l16     = lane & 15;

    const int e0  = rowptr[wid];
    const int deg = rowptr[wid + 1] - e0;

    float a[8];
#pragma unroll
    for (int k = 0; k < 8; ++k) a[k] = 0.0f;

    for (int base = 0; base < deg; base += 64) {
        const int nch = min(64, deg - base);
        int myc = (lane < nch) ? col[e0 + base + lane] : 0;

        int i = 0;
        for (; i + 7 < nch; i += 8) {
            const int s0 = __shfl(myc, i + quarter);
            const int s1 = __shfl(myc, i + 4 + quarter);
            const uint4 v0 = *reinterpret_cast<const uint4*>(
                &A[(size_t)s0 * KDIM + D + l16 * 8]);
            const uint4 v1 = *reinterpret_cast<const uint4*>(
                &A[(size_t)s1 * KDIM + D + l16 * 8]);
            a[0] += bflo(v0.x) + bflo(v1.x); a[1] += bfhi(v0.x) + bfhi(v1.x);
            a[2] += bflo(v0.y) + bflo(v1.y); a[3] += bfhi(v0.y) + bfhi(v1.y);
            a[4] += bflo(v0.z) + bflo(v1.z); a[5] += bfhi(v0.z) + bfhi(v1.z);
            a[6] += bflo(v0.w) + bflo(v1.w); a[7] += bfhi(v0.w) + bfhi(v1.w);
        }
        for (; i + 3 < nch; i += 4) {
            const int s = __shfl(myc, i + quarter);
            const uint4 v = *reinterpret_cast<const uint4*>(
                &A[(size_t)s * KDIM + D + l16 * 8]);
            a[0] += bflo(v.x); a[1] += bfhi(v.x);
            a[2] += bflo(v.y); a[3] += bfhi(v.y);
            a[4] += bflo(v.z); a[5] += bfhi(v.z);
            a[6] += bflo(v.w); a[7] += bfhi(v.w);
        }
        if (i < nch) {
            const int idx = i + quarter;
            const int s = __shfl(myc, idx < nch ? idx : nch - 1);
            if (idx < nch) {
                const uint4 v = *reinterpret_cast<const uint4*>(
                    &A[(size_t)s * KDIM + D + l16 * 8]);
                a[0] += bflo(v.x); a[1] += bfhi(v.x);
                a[2] += bflo(v.y); a[3] += bfhi(v.y);
                a[4] += bflo(v.z); a[5] += bfhi(v.z);
                a[6] += bflo(v.w); a[7] += bfhi(v.w);
            }
        }
    }

#pragma unroll
    for (int k = 0; k < 8; ++k) {
        a[k] += __shfl_down(a[k], 32);
        a[k] += __shfl_down(a[k], 16);
    }

    if (lane < 16) {
        const float inv = deg > 0 ? 1.0f / (float)deg : 0.0f;
        uint4 o;
        o.x = ((unsigned int)f2bf(a[1] * inv) << 16) | f2bf(a[0] * inv);
        o.y = ((unsigned int)f2bf(a[3] * inv) << 16) | f2bf(a[2] * inv);
        o.z = ((unsigned int)f2bf(a[5] * inv) << 16) | f2bf(a[4] * inv);
        o.w = ((unsigned int)f2bf(a[7] * inv) << 16) | f2bf(a[6] * inv);
        *reinterpret_cast<uint4*>(&out[(size_t)wid * KDIM + l16 * 8]) = o;
    }
}

// ---------------------------------------------------------------------------
// MFMA GEMM: out[n][j] = relu( A[n][0..255] . Wt[j][0..255] + bias[j] )
// ---------------------------------------------------------------------------
template <int WRITE_BF16>
__global__ __launch_bounds__(256)
void sage_gemm(const unsigned short* __restrict__ A,
               const unsigned short* __restrict__ Wt,
               const float* __restrict__ bias,
               float* __restrict__ out_f32,
               unsigned short* __restrict__ out_bf16) {
    const int w = threadIdx.x >> 6;
    const int lane = threadIdx.x & 63;
    const int l16 = lane & 15;
    const int lk = lane >> 4;          // 0..3
    const int row0 = blockIdx.x * 64;
    const int wc = w * 32;             // wave col base

    short8 bfrag[2][8];
#pragma unroll
    for (int c = 0; c < 2; ++c)
#pragma unroll
        for (int kk = 0; kk < 8; ++kk)
            bfrag[c][kk] = *reinterpret_cast<const short8*>(
                &Wt[(size_t)(wc + c * 16 + l16) * KDIM + kk * 32 + lk * 8]);

    f32x4 acc[4][2];
#pragma unroll
    for (int r = 0; r < 4; ++r)
#pragma unroll
        for (int c = 0; c < 2; ++c) acc[r][c] = (f32x4)0.0f;

#pragma unroll
    for (int kk = 0; kk < 8; ++kk) {
        short8 af[4];
#pragma unroll
        for (int r = 0; r < 4; ++r) {
            int row = row0 + r * 16 + l16;
            if (row >= N_NODES) row = N_NODES - 1;  // clamp; values unused
            af[r] = *reinterpret_cast<const short8*>(
                &A[(size_t)row * KDIM + kk * 32 + lk * 8]);
        }
#pragma unroll
        for (int r = 0; r < 4; ++r)
#pragma unroll
            for (int c = 0; c < 2; ++c)
                acc[r][c] = __builtin_amdgcn_mfma_f32_16x16x32_bf16(
                    af[r], bfrag[c][kk], acc[r][c], 0, 0, 0);
    }

    // epilogue: C/D layout col=lane&15, row=(lane>>4)*4+reg  [verified m89/m91]
#pragma unroll
    for (int c = 0; c < 2; ++c) {
        int colj = wc + c * 16 + l16;
        float bv = bias[colj];
#pragma unroll
        for (int r = 0; r < 4; ++r) {
#pragma unroll
            for (int q = 0; q < 4; ++q) {
                int row = row0 + r * 16 + lk * 4 + q;
                if (row < N_NODES) {
                    float v = acc[r][c][q] + bv;
                    v = v > 0.f ? v : 0.f;
                    if (WRITE_BF16)
                        out_bf16[(size_t)row * KDIM + D + colj] = f2bf(v);
                    else
                        out_f32[(size_t)row * D + colj] = v;
                }
            }
        }
    }
}

extern "C" void kernel_launch(void* const* d_in, const int* in_sizes, int n_in,
                              void* d_out, int out_size, void* d_ws, size_t ws_size,
                              hipStream_t stream) {
    const float* x   = (const float*)d_in[0];
    const int*   ei  = (const int*)  d_in[1];
    const float* W1l = (const float*)d_in[2];
    const float* b1  = (const float*)d_in[3];
    const float* W1r = (const float*)d_in[4];
    const float* W2l = (const float*)d_in[5];
    const float* b2  = (const float*)d_in[6];
    const float* W2r = (const float*)d_in[7];
    float*       out = (float*)d_out;

    const int n_edges = in_sizes[1] / 2;
    const int* src = ei;
    const int* dst = ei + n_edges;

    // workspace layout (A first for 16B alignment)
    char* ws = (char*)d_ws;
    unsigned short* A   = (unsigned short*)ws;                 // N*256 bf16
    unsigned short* Wt1 = A + (size_t)N_NODES * KDIM;          // 128*256
    unsigned short* Wt2 = Wt1 + 128 * KDIM;                    // 128*256
    int* cnt    = (int*)(Wt2 + 128 * KDIM);                    // N
    int* rowptr = cnt + N_NODES;                               // N+1
    int* cursor = rowptr + (N_NODES + 1);                      // N
    int* bagg   = cursor + N_NODES;                            // SCAN_NB
    int* bflag  = bagg + SCAN_NB;                              // SCAN_NB
    int* col    = bflag + SCAN_NB;                             // E

    // ---- prep: zero cnt/flags + convert W + convert x (1 launch) ----
    prep_kernel<<<SCAN_NB + CW_NB + CX_NB, 256, 0, stream>>>(
        cnt, bflag, W1l, W1r, W2l, W2r, Wt1, Wt2, x, A);

    // ---- CSR build: hist -> single-pass scan -> binned scatter ----
    hist_kernel<<<(n_edges + 255) / 256, 256, 0, stream>>>(dst, cnt, n_edges);
    scan_lookback<<<SCAN_NB, SCAN_B, 0, stream>>>(cnt, rowptr, cursor, bagg,
                                                  bflag, n_edges);
    const int nchunks = (n_edges + SC_CHUNK - 1) / SC_CHUNK;
    scatter_binned<<<nchunks * NR, 256, 0, stream>>>(src, dst, cursor, col,
                                                     n_edges);

    const int gemm_grid = (N_NODES + 63) / 64;

    // ---- layer 1 ----
    agg_bf16<<<(N_NODES * 64 + 255) / 256, 256, 0, stream>>>(A, rowptr, col, A);
    sage_gemm<1><<<gemm_grid, 256, 0, stream>>>(A, Wt1, b1, nullptr, A);

    // ---- layer 2 ----
    agg_bf16<<<(N_NODES * 64 + 255) / 256, 256, 0, stream>>>(A, rowptr, col, A);
    sage_gemm<0><<<gemm_grid, 256, 0, stream>>>(A, Wt2, b2, out, nullptr);
}

// Round 9
// 172.770 us; speedup vs baseline: 8.5982x; 1.1097x over previous
//
#include <hip/hip_runtime.h>

#define N_NODES 50000
#define D 128
#define KDIM 256
#define SCAN_B 256
#define SCAN_NB ((N_NODES + SCAN_B - 1) / SCAN_B)  // 196
#define CW_NB 256                                   // convert_w blocks
#define CX_NB ((N_NODES * 32) / 256)                // 6250 convert_x blocks
#define NR 8                                        // XCD bins
#define RNG ((N_NODES + NR - 1) / NR)               // 6250 nodes per bin
#define SC_CHUNK 4096                               // edges per scatter chunk

typedef __attribute__((ext_vector_type(8))) short short8;
typedef __attribute__((ext_vector_type(4))) float f32x4;

__device__ __forceinline__ unsigned short f2bf(float f) {
    unsigned int u = __builtin_bit_cast(unsigned int, f);
    u += 0x7FFFu + ((u >> 16) & 1u);
    return (unsigned short)(u >> 16);
}
__device__ __forceinline__ float bflo(unsigned int u) {
    return __builtin_bit_cast(float, u << 16);
}
__device__ __forceinline__ float bfhi(unsigned int u) {
    return __builtin_bit_cast(float, u & 0xFFFF0000u);
}

// ---------------------------------------------------------------------------
// prep: fused {zero cnt+flags | convert W | convert x}, branch per block range
// ---------------------------------------------------------------------------
__global__ void prep_kernel(int* __restrict__ cnt, int* __restrict__ bflag,
                            const float* __restrict__ Wl1, const float* __restrict__ Wr1,
                            const float* __restrict__ Wl2, const float* __restrict__ Wr2,
                            unsigned short* __restrict__ Wt1, unsigned short* __restrict__ Wt2,
                            const float* __restrict__ x, unsigned short* __restrict__ A) {
    const int bid = blockIdx.x;
    const int t = threadIdx.x;
    if (bid < SCAN_NB) {
        int i = bid * SCAN_B + t;
        if (i < N_NODES) cnt[i] = 0;
        if (t == 0) bflag[bid] = 0;
    } else if (bid < SCAN_NB + CW_NB) {
        if (t < 128) {
            int wb = bid - SCAN_NB;
            int layer = wb >> 7;
            int j = wb & 127;
            const float* Wl = layer ? Wl2 : Wl1;
            const float* Wr = layer ? Wr2 : Wr1;
            unsigned short* Wt = layer ? Wt2 : Wt1;
            Wt[(size_t)j * KDIM + t]     = f2bf(Wl[t * D + j]);
            Wt[(size_t)j * KDIM + D + t] = f2bf(Wr[t * D + j]);
        }
    } else {
        int g = (bid - SCAN_NB - CW_NB) * 256 + t;
        int n = g >> 5;
        int c4 = (g & 31) * 4;
        if (n < N_NODES) {
            float4 v = *reinterpret_cast<const float4*>(&x[(size_t)n * D + c4]);
            ushort4 o;
            o.x = f2bf(v.x); o.y = f2bf(v.y); o.z = f2bf(v.z); o.w = f2bf(v.w);
            *reinterpret_cast<ushort4*>(&A[(size_t)n * KDIM + D + c4]) = o;
        }
    }
}

// ---------------------------------------------------------------------------
// CSR build step 1: histogram of dst
// ---------------------------------------------------------------------------
__global__ void hist_kernel(const int* __restrict__ dst,
                            int* __restrict__ cnt, int n_edges) {
    int e = blockIdx.x * blockDim.x + threadIdx.x;
    if (e < n_edges) atomicAdd(&cnt[dst[e]], 1);
}

// ---------------------------------------------------------------------------
// CSR build step 2: single-pass exclusive scan (decoupled lookback)
// ---------------------------------------------------------------------------
__global__ __launch_bounds__(SCAN_B)
void scan_lookback(const int* __restrict__ cnt,
                   int* __restrict__ rowptr,
                   int* __restrict__ cursor,
                   int* __restrict__ bagg,
                   int* __restrict__ bflag, int n_edges) {
    __shared__ int s[SCAN_B];
    __shared__ int sh_prefix;
    const int bid = blockIdx.x;
    const int t = threadIdx.x;
    const int i = bid * SCAN_B + t;
    const int v = (i < N_NODES) ? cnt[i] : 0;
    s[t] = v;
    __syncthreads();
    for (int off = 1; off < SCAN_B; off <<= 1) {
        int tmp = (t >= off) ? s[t - off] : 0;
        __syncthreads();
        s[t] += tmp;
        __syncthreads();
    }
    if (t == 0) {
        bagg[bid] = s[SCAN_B - 1];
        __hip_atomic_store(&bflag[bid], 1, __ATOMIC_RELEASE,
                           __HIP_MEMORY_SCOPE_AGENT);
        sh_prefix = 0;
        if (bid == 0) rowptr[N_NODES] = n_edges;  // every dst in [0,N)
    }
    if (bid > 0 && t < 64) {
        int part = 0;
        for (int j = t; j < bid; j += 64) {
            while (__hip_atomic_load(&bflag[j], __ATOMIC_ACQUIRE,
                                     __HIP_MEMORY_SCOPE_AGENT) == 0) {}
            part += bagg[j];
        }
#pragma unroll
        for (int off = 32; off > 0; off >>= 1) part += __shfl_down(part, off);
        if (t == 0) sh_prefix = part;
    }
    __syncthreads();
    if (i < N_NODES) {
        int ex = sh_prefix + s[t] - v;
        rowptr[i] = ex;
        cursor[i] = ex;
    }
}

// ---------------------------------------------------------------------------
// CSR build step 3: XCD-binned scatter (write locality per dst range)
// ---------------------------------------------------------------------------
__global__ void scatter_binned(const int* __restrict__ src,
                               const int* __restrict__ dst,
                               int* __restrict__ cursor,
                               int* __restrict__ col, int n_edges) {
    const int r = blockIdx.x & (NR - 1);
    const int c = blockIdx.x >> 3;
    const int lo = r * RNG;
    const int hi = min(N_NODES, lo + RNG);
    const int ebase = c * SC_CHUNK;
    const int eend = min(n_edges, ebase + SC_CHUNK);
    for (int e = ebase + threadIdx.x; e < eend; e += 256) {
        int d = dst[e];
        if (d >= lo && d < hi) {
            int p = atomicAdd(&cursor[d], 1);
            col[p] = src[e];
        }
    }
}

// ---------------------------------------------------------------------------
// Fused SAGE layer: stage 1 = quarter-wave-per-node mean-agg into LDS
// (XOR-swizzled), stage 2 = MFMA GEMM (mean from LDS, self from global).
// LAYER 1: features at A[.][D..2D), h written bf16 to A[.][0..D)  (disjoint
//          column ranges -> no cross-block race).
// LAYER 2: features at A[.][0..D), output fp32 to out.
// ---------------------------------------------------------------------------
template <int LAYER>
__global__ __launch_bounds__(256)
void sage_layer_fused(const unsigned short* __restrict__ A,
                      unsigned short* __restrict__ A_wr,
                      const int* __restrict__ rowptr,
                      const int* __restrict__ col,
                      const unsigned short* __restrict__ Wt,
                      const float* __restrict__ bias,
                      float* __restrict__ out_f32) {
    constexpr int FEAT = (LAYER == 1) ? D : 0;
    __shared__ unsigned short ms[64 * D];  // 16 KB, swizzled [64][128] bf16

    const int row0 = blockIdx.x * 64;
    const int tid = threadIdx.x;

    // ---- stage 1: mean-aggregate; quarter-wave (16 lanes) per node ----
    {
        const int qid = tid >> 4;    // 0..15
        const int lq = tid & 15;     // lane within quarter; owns 16B = 8 cols
        for (int s = 0; s < 4; ++s) {
            const int lr = s * 16 + qid;    // local row 0..63
            const int node = row0 + lr;
            float a[8] = {0.f, 0.f, 0.f, 0.f, 0.f, 0.f, 0.f, 0.f};
            int deg = 0;
            if (node < N_NODES) {
                const int e0 = rowptr[node];
                deg = rowptr[node + 1] - e0;
                for (int base = 0; base < deg; base += 16) {
                    const int nch = min(16, deg - base);
                    int myc = (lq < nch) ? col[e0 + base + lq] : 0;
                    int i = 0;
                    for (; i + 1 < nch; i += 2) {
                        const int s0 = __shfl(myc, i, 16);
                        const int s1 = __shfl(myc, i + 1, 16);
                        const uint4 v0 = *reinterpret_cast<const uint4*>(
                            &A[(size_t)s0 * KDIM + FEAT + lq * 8]);
                        const uint4 v1 = *reinterpret_cast<const uint4*>(
                            &A[(size_t)s1 * KDIM + FEAT + lq * 8]);
                        a[0] += bflo(v0.x) + bflo(v1.x);
                        a[1] += bfhi(v0.x) + bfhi(v1.x);
                        a[2] += bflo(v0.y) + bflo(v1.y);
                        a[3] += bfhi(v0.y) + bfhi(v1.y);
                        a[4] += bflo(v0.z) + bflo(v1.z);
                        a[5] += bfhi(v0.z) + bfhi(v1.z);
                        a[6] += bflo(v0.w) + bflo(v1.w);
                        a[7] += bfhi(v0.w) + bfhi(v1.w);
                    }
                    if (i < nch) {
                        const int s0 = __shfl(myc, i, 16);
                        const uint4 v0 = *reinterpret_cast<const uint4*>(
                            &A[(size_t)s0 * KDIM + FEAT + lq * 8]);
                        a[0] += bflo(v0.x); a[1] += bfhi(v0.x);
                        a[2] += bflo(v0.y); a[3] += bfhi(v0.y);
                        a[4] += bflo(v0.z); a[5] += bfhi(v0.z);
                        a[6] += bflo(v0.w); a[7] += bfhi(v0.w);
                    }
                }
            }
            const float inv = deg > 0 ? 1.0f / (float)deg : 0.0f;
            uint4 o;
            o.x = ((unsigned int)f2bf(a[1] * inv) << 16) | f2bf(a[0] * inv);
            o.y = ((unsigned int)f2bf(a[3] * inv) << 16) | f2bf(a[2] * inv);
            o.z = ((unsigned int)f2bf(a[5] * inv) << 16) | f2bf(a[4] * inv);
            o.w = ((unsigned int)f2bf(a[7] * inv) << 16) | f2bf(a[6] * inv);
            // XOR-swizzled store: byte = lr*256 + ((lq*16) ^ ((lr&7)<<4))
            char* rowb = reinterpret_cast<char*>(ms) + lr * 256;
            *reinterpret_cast<uint4*>(rowb + ((lq * 16) ^ ((lr & 7) << 4))) = o;
        }
    }
    __syncthreads();

    // ---- stage 2: MFMA GEMM; wave w owns 32 output cols, 64 rows/block ----
    const int w = tid >> 6;
    const int lane = tid & 63;
    const int l16 = lane & 15;
    const int lk = lane >> 4;          // 0..3
    const int wc = w * 32;

    short8 bfrag[2][8];
#pragma unroll
    for (int c = 0; c < 2; ++c)
#pragma unroll
        for (int kk = 0; kk < 8; ++kk)
            bfrag[c][kk] = *reinterpret_cast<const short8*>(
                &Wt[(size_t)(wc + c * 16 + l16) * KDIM + kk * 32 + lk * 8]);

    f32x4 acc[4][2];
#pragma unroll
    for (int r = 0; r < 4; ++r)
#pragma unroll
        for (int c = 0; c < 2; ++c) acc[r][c] = (f32x4)0.0f;

    // kk 0..3: mean term (k=0..127) from swizzled LDS
#pragma unroll
    for (int kk = 0; kk < 4; ++kk) {
        short8 af[4];
#pragma unroll
        for (int r = 0; r < 4; ++r) {
            const int lr = r * 16 + l16;
            const int cb = kk * 64 + lk * 16;  // byte col within row
            const char* rowb = reinterpret_cast<const char*>(ms) + lr * 256;
            af[r] = *reinterpret_cast<const short8*>(
                rowb + (cb ^ ((lr & 7) << 4)));
        }
#pragma unroll
        for (int r = 0; r < 4; ++r)
#pragma unroll
            for (int c = 0; c < 2; ++c)
                acc[r][c] = __builtin_amdgcn_mfma_f32_16x16x32_bf16(
                    af[r], bfrag[c][kk], acc[r][c], 0, 0, 0);
    }

    // kk 4..7: self term (k=128..255) from global features
#pragma unroll
    for (int kk = 4; kk < 8; ++kk) {
        short8 af[4];
#pragma unroll
        for (int r = 0; r < 4; ++r) {
            int row = row0 + r * 16 + l16;
            if (row >= N_NODES) row = N_NODES - 1;  // clamp; values unused
            af[r] = *reinterpret_cast<const short8*>(
                &A[(size_t)row * KDIM + FEAT + (kk - 4) * 32 + lk * 8]);
        }
#pragma unroll
        for (int r = 0; r < 4; ++r)
#pragma unroll
            for (int c = 0; c < 2; ++c)
                acc[r][c] = __builtin_amdgcn_mfma_f32_16x16x32_bf16(
                    af[r], bfrag[c][kk], acc[r][c], 0, 0, 0);
    }

    // epilogue: C/D layout col=lane&15, row=(lane>>4)*4+reg  [verified m89/m91]
#pragma unroll
    for (int c = 0; c < 2; ++c) {
        int colj = wc + c * 16 + l16;
        float bv = bias[colj];
#pragma unroll
        for (int r = 0; r < 4; ++r) {
#pragma unroll
            for (int q = 0; q < 4; ++q) {
                int row = row0 + r * 16 + lk * 4 + q;
                if (row < N_NODES) {
                    float v = acc[r][c][q] + bv;
                    v = v > 0.f ? v : 0.f;
                    if (LAYER == 1)
                        A_wr[(size_t)row * KDIM + colj] = f2bf(v);  // h -> cols 0..127
                    else
                        out_f32[(size_t)row * D + colj] = v;
                }
            }
        }
    }
}

extern "C" void kernel_launch(void* const* d_in, const int* in_sizes, int n_in,
                              void* d_out, int out_size, void* d_ws, size_t ws_size,
                              hipStream_t stream) {
    const float* x   = (const float*)d_in[0];
    const int*   ei  = (const int*)  d_in[1];
    const float* W1l = (const float*)d_in[2];
    const float* b1  = (const float*)d_in[3];
    const float* W1r = (const float*)d_in[4];
    const float* W2l = (const float*)d_in[5];
    const float* b2  = (const float*)d_in[6];
    const float* W2r = (const float*)d_in[7];
    float*       out = (float*)d_out;

    const int n_edges = in_sizes[1] / 2;
    const int* src = ei;
    const int* dst = ei + n_edges;

    // workspace layout (A first for 16B alignment)
    char* ws = (char*)d_ws;
    unsigned short* A   = (unsigned short*)ws;                 // N*256 bf16
    unsigned short* Wt1 = A + (size_t)N_NODES * KDIM;          // 128*256
    unsigned short* Wt2 = Wt1 + 128 * KDIM;                    // 128*256
    int* cnt    = (int*)(Wt2 + 128 * KDIM);                    // N
    int* rowptr = cnt + N_NODES;                               // N+1
    int* cursor = rowptr + (N_NODES + 1);                      // N
    int* bagg   = cursor + N_NODES;                            // SCAN_NB
    int* bflag  = bagg + SCAN_NB;                              // SCAN_NB
    int* col    = bflag + SCAN_NB;                             // E

    // ---- prep: zero cnt/flags + convert W + convert x (1 launch) ----
    prep_kernel<<<SCAN_NB + CW_NB + CX_NB, 256, 0, stream>>>(
        cnt, bflag, W1l, W1r, W2l, W2r, Wt1, Wt2, x, A);

    // ---- CSR build: hist -> single-pass scan -> binned scatter ----
    hist_kernel<<<(n_edges + 255) / 256, 256, 0, stream>>>(dst, cnt, n_edges);
    scan_lookback<<<SCAN_NB, SCAN_B, 0, stream>>>(cnt, rowptr, cursor, bagg,
                                                  bflag, n_edges);
    const int nchunks = (n_edges + SC_CHUNK - 1) / SC_CHUNK;
    scatter_binned<<<nchunks * NR, 256, 0, stream>>>(src, dst, cursor, col,
                                                     n_edges);

    const int grid = (N_NODES + 63) / 64;  // 782

    // ---- fused layers ----
    sage_layer_fused<1><<<grid, 256, 0, stream>>>(A, A, rowptr, col, Wt1, b1,
                                                  nullptr);
    sage_layer_fused<2><<<grid, 256, 0, stream>>>(A, A, rowptr, col, Wt2, b2,
                                                  out);
}